// Round 7
// baseline (275.077 us; speedup 1.0000x reference)
//
#include <hip/hip_runtime.h>
#include <hip/hip_bf16.h>

#define N_NODES 4096
#define DIN     512
#define FDIM    64
#define NHEADS  8
#define DOUT    16
#define MAXN    512

static __device__ __forceinline__ float us2f(unsigned short u) {
    union { unsigned int i; float f; } cv; cv.i = ((unsigned int)u) << 16; return cv.f;
}
static __device__ __forceinline__ unsigned short f2us(float v) {
    __hip_bfloat16 b = __float2bfloat16(v);
    return *(const unsigned short*)&b;
}

// K0: dtype detect (adj[0][0] is self-loop 1.0; fp32 low ushort = 0)
__global__ void detect_kernel(const unsigned short* __restrict__ adj, int* __restrict__ flag)
{
    if (threadIdx.x == 0) *flag = (adj[0] == 0) ? 1 : 0;
}

// K1: ROW-oriented neighbor lists (verified r4): node n attends over {m : adj[n][m]!=0}
__global__ __launch_bounds__(256) void build_nbr_kernel(
    const void* __restrict__ adj, const int* __restrict__ flag,
    int* __restrict__ cnt, int* __restrict__ nbr)
{
    const int n = blockIdx.x;
    const int f32 = *flag;
    __shared__ int c;
    if (threadIdx.x == 0) c = 0;
    __syncthreads();
    if (f32) {
        const unsigned int* row = (const unsigned int*)adj + (size_t)n * N_NODES;
        for (int m = threadIdx.x; m < N_NODES; m += 256) {
            if (row[m]) { int p = atomicAdd(&c, 1); if (p < MAXN) nbr[(size_t)n * MAXN + p] = m; }
        }
    } else {
        const unsigned short* row = (const unsigned short*)adj + (size_t)n * N_NODES;
        for (int m = threadIdx.x; m < N_NODES; m += 256) {
            if (row[m]) { int p = atomicAdd(&c, 1); if (p < MAXN) nbr[(size_t)n * MAXN + p] = m; }
        }
    }
    __syncthreads();
    if (threadIdx.x == 0) cnt[n] = (c < MAXN) ? c : MAXN;
}

// K2: small tensors -> canonical fp32: a1c[512]|a2c[512]|Woc[8192]|ao1c[16]|ao2c[16]
__global__ __launch_bounds__(256) void conv_small_kernel(
    const void* __restrict__ a1, const void* __restrict__ a2, const void* __restrict__ Wo,
    const void* __restrict__ ao1, const void* __restrict__ ao2,
    const int* __restrict__ flag, float* __restrict__ dst)
{
    const int f32 = *flag;
    const void* srcs[5] = { a1, a2, Wo, ao1, ao2 };
    const int   szs[5]  = { 512, 512, 8192, 16, 16 };
    int base = 0;
    for (int s = 0; s < 5; ++s) {
        if (f32) {
            for (int i = threadIdx.x; i < szs[s]; i += 256)
                dst[base + i] = ((const float*)srcs[s])[i];
        } else {
            for (int i = threadIdx.x; i < szs[s]; i += 256)
                dst[base + i] = us2f(((const unsigned short*)srcs[s])[i]);
        }
        base += szs[s];
    }
}

// K3: Wh[h,n,f] = sum_d X[n,d] W[h,d,f]; verified r4; bf16 store
__global__ __launch_bounds__(256) void wh_gemm_kernel(
    const void* __restrict__ X, const void* __restrict__ W,
    const int* __restrict__ flag, unsigned short* __restrict__ Whb)
{
    __shared__ float As[16][65];
    __shared__ float Bs[16][65];
    const int f32 = *flag;
    const int bn = blockIdx.x;
    const int bm = blockIdx.y;
    const int tid = threadIdx.x;
    const int tx = tid & 15;
    const int ty = tid >> 4;
    float acc[4][4] = {};
    for (int k0 = 0; k0 < DIN; k0 += 16) {
        if (f32) {
            for (int l = tid; l < 64 * 16; l += 256) {
                int i = l >> 4, kk = l & 15;
                As[kk][i] = ((const float*)X)[(size_t)(bm * 64 + i) * DIN + k0 + kk];
            }
            for (int l = tid; l < 16 * 64; l += 256) {
                int kk = l >> 6, j = l & 63;
                Bs[kk][j] = ((const float*)W)[(size_t)bn * DIN * FDIM + (k0 + kk) * FDIM + j];
            }
        } else {
            for (int l = tid; l < 64 * 16; l += 256) {
                int i = l >> 4, kk = l & 15;
                As[kk][i] = us2f(((const unsigned short*)X)[(size_t)(bm * 64 + i) * DIN + k0 + kk]);
            }
            for (int l = tid; l < 16 * 64; l += 256) {
                int kk = l >> 6, j = l & 63;
                Bs[kk][j] = us2f(((const unsigned short*)W)[(size_t)bn * DIN * FDIM + (k0 + kk) * FDIM + j]);
            }
        }
        __syncthreads();
#pragma unroll
        for (int kk = 0; kk < 16; ++kk) {
            float a[4], b[4];
#pragma unroll
            for (int u = 0; u < 4; ++u) a[u] = As[kk][ty * 4 + u];
#pragma unroll
            for (int v = 0; v < 4; ++v) b[v] = Bs[kk][tx * 4 + v];
#pragma unroll
            for (int u = 0; u < 4; ++u)
#pragma unroll
                for (int v = 0; v < 4; ++v) acc[u][v] += a[u] * b[v];
        }
        __syncthreads();
    }
#pragma unroll
    for (int u = 0; u < 4; ++u) {
        int n = bm * 64 + ty * 4 + u;
#pragma unroll
        for (int v = 0; v < 4; ++v)
            Whb[((size_t)bn * N_NODES + n) * FDIM + tx * 4 + v] = f2us(acc[u][v]);
    }
}

// K4: f1[h,n], f2[h,n]  (verified r4)
__global__ __launch_bounds__(256) void f12_kernel(
    const unsigned short* __restrict__ Whb,
    const float* __restrict__ a1c, const float* __restrict__ a2c,
    float* __restrict__ f1, float* __restrict__ f2)
{
    int idx = blockIdx.x * 256 + threadIdx.x;
    int h = idx >> 12;
    const unsigned short* row = Whb + (size_t)idx * FDIM;
    float s1 = 0.f, s2 = 0.f;
#pragma unroll
    for (int f = 0; f < FDIM; ++f) {
        float v = us2f(row[f]);
        s1 += v * a1c[h * FDIM + f];
        s2 += v * a2c[h * FDIM + f];
    }
    f1[idx] = s1;
    f2[idx] = s2;
}

// K5: layer-1 sparse attention + ELU -> catb (verified r4)
__global__ __launch_bounds__(256) void attn1_kernel(
    const unsigned short* __restrict__ Whb,
    const float* __restrict__ f1, const float* __restrict__ f2,
    const int* __restrict__ cnt, const int* __restrict__ nbr,
    unsigned short* __restrict__ catb)
{
    const int n = blockIdx.x;
    const int tid = threadIdx.x;
    const int wid = tid >> 6;
    const int lane = tid & 63;
    __shared__ int sh_m[MAXN];
    __shared__ float sh_s[4][MAXN];
    const int c0 = cnt[n];
    const int c = (c0 < MAXN) ? c0 : MAXN;
    for (int k = tid; k < c; k += 256) sh_m[k] = nbr[(size_t)n * MAXN + k];
    __syncthreads();
    for (int hh = 0; hh < 2; ++hh) {
        const int h = wid * 2 + hh;
        const float f1v = f1[h * N_NODES + n];
        float mx = -1e30f;
        for (int k = lane; k < c; k += 64) {
            float s = f1v + f2[h * N_NODES + sh_m[k]];
            s = (s >= 0.f) ? s : 0.2f * s;
            sh_s[wid][k] = s;
            mx = fmaxf(mx, s);
        }
#pragma unroll
        for (int off = 32; off; off >>= 1) mx = fmaxf(mx, __shfl_xor(mx, off));
        float sum = 0.f;
        for (int k = lane; k < c; k += 64) {
            float e = __expf(sh_s[wid][k] - mx);
            sh_s[wid][k] = e;
            sum += e;
        }
#pragma unroll
        for (int off = 32; off; off >>= 1) sum += __shfl_xor(sum, off);
        const float inv = (sum > 0.f) ? 1.f / sum : 0.f;
        float acc = 0.f;
        for (int k = 0; k < c; ++k)
            acc += sh_s[wid][k] * us2f(Whb[((size_t)h * N_NODES + sh_m[k]) * FDIM + lane]);
        acc *= inv;
        acc = (acc > 0.f) ? acc : expm1f(acc);
        catb[(size_t)n * (NHEADS * FDIM) + h * FDIM + lane] = f2us(acc);
        __syncthreads();
    }
}

// K6: Who = cat @ Wo  (verified r4)
__global__ __launch_bounds__(256) void who_kernel(
    const unsigned short* __restrict__ catb, const float* __restrict__ Woc,
    float* __restrict__ Who)
{
    __shared__ float sWo[DIN * DOUT];
    for (int l = threadIdx.x; l < DIN * DOUT; l += 256) sWo[l] = Woc[l];
    __syncthreads();
    const int i = threadIdx.x >> 4;
    const int j = threadIdx.x & 15;
    const int n = blockIdx.x * 16 + i;
    const unsigned short* crow = catb + (size_t)n * DIN;
    float acc = 0.f;
    for (int d = 0; d < DIN; ++d) acc += us2f(crow[d]) * sWo[d * DOUT + j];
    Who[n * DOUT + j] = acc;
}

// K7: g1, g2  (verified r4)
__global__ __launch_bounds__(256) void g12_kernel(
    const float* __restrict__ Who,
    const float* __restrict__ ao1c, const float* __restrict__ ao2c,
    float* __restrict__ g1, float* __restrict__ g2)
{
    int n = blockIdx.x * 256 + threadIdx.x;
    float s1 = 0.f, s2 = 0.f;
#pragma unroll
    for (int j = 0; j < DOUT; ++j) {
        float v = Who[n * DOUT + j];
        s1 += v * ao1c[j];
        s2 += v * ao2c[j];
    }
    g1[n] = s1;
    g2[n] = s2;
}

// K8: output sparse attention. OUTPUT DTYPE FIX: fp32 store when inputs are
// fp32 (reference output dtype = float32); bf16 store otherwise.
__global__ __launch_bounds__(64) void attn2_kernel(
    const float* __restrict__ Who,
    const float* __restrict__ g1, const float* __restrict__ g2,
    const int* __restrict__ cnt, const int* __restrict__ nbr,
    const int* __restrict__ flag, void* __restrict__ out)
{
    const int n = blockIdx.x;
    const int lane = threadIdx.x;
    __shared__ float sh_s[MAXN];
    __shared__ int sh_m[MAXN];
    const int c0 = cnt[n];
    const int c = (c0 < MAXN) ? c0 : MAXN;
    for (int k = lane; k < c; k += 64) sh_m[k] = nbr[(size_t)n * MAXN + k];
    __syncthreads();
    const float gn = g1[n];
    float mx = -1e30f;
    for (int k = lane; k < c; k += 64) {
        float s = gn + g2[sh_m[k]];
        s = (s >= 0.f) ? s : 0.2f * s;
        sh_s[k] = s;
        mx = fmaxf(mx, s);
    }
#pragma unroll
    for (int off = 32; off; off >>= 1) mx = fmaxf(mx, __shfl_xor(mx, off));
    __syncthreads();
    float sum = 0.f;
    for (int k = lane; k < c; k += 64) {
        float e = __expf(sh_s[k] - mx);
        sh_s[k] = e;
        sum += e;
    }
#pragma unroll
    for (int off = 32; off; off >>= 1) sum += __shfl_xor(sum, off);
    __syncthreads();
    const float inv = (sum > 0.f) ? 1.f / sum : 0.f;
    if (lane < DOUT) {
        float acc = 0.f;
        for (int k = 0; k < c; ++k) acc += sh_s[k] * Who[sh_m[k] * DOUT + lane];
        acc *= inv;
        if (*flag) ((float*)out)[n * DOUT + lane] = acc;
        else       ((unsigned short*)out)[n * DOUT + lane] = f2us(acc);
    }
}

__global__ void wsfail_kernel(float* __restrict__ out)
{
    if (threadIdx.x == 0) out[0] = 129.f;
}

// ---------------------------------------------------------------------------
extern "C" void kernel_launch(void* const* d_in, const int* in_sizes, int n_in,
                              void* d_out, int out_size, void* d_ws, size_t ws_size,
                              hipStream_t stream)
{
    const void* adj = d_in[0];
    const void* X   = d_in[1];
    const void* W   = d_in[2];
    const void* a1  = d_in[3];
    const void* a2  = d_in[4];
    const void* Wo  = d_in[5];
    const void* ao1 = d_in[6];
    const void* ao2 = d_in[7];

    const size_t NEEDED = 17400000;   // verified available in r4 (no wsfail marker)
    if (ws_size < NEEDED) { wsfail_kernel<<<1, 64, 0, stream>>>((float*)d_out); return; }

    int* flag = (int*)d_ws;                         // 1
    int* cnt  = flag + 1;                           // 4096
    int* nbr  = cnt + 4096;                         // 4096*512
    float* smalls = (float*)(nbr + 2097152);        // 9248
    float* a1c  = smalls;
    float* a2c  = smalls + 512;
    float* Woc  = smalls + 1024;
    float* ao1c = smalls + 9216;
    float* ao2c = smalls + 9232;
    float* f1   = smalls + 9248;                    // 32768
    float* f2   = f1 + 32768;                       // 32768
    float* Who  = f2 + 32768;                       // 65536
    float* g1   = Who + 65536;                      // 4096
    float* g2   = g1 + 4096;                        // 4096
    unsigned short* Whb  = (unsigned short*)(g2 + 4096);  // 2097152 us
    unsigned short* catb = Whb + 2097152;                 // 2097152 us

    detect_kernel<<<1, 64, 0, stream>>>((const unsigned short*)adj, flag);
    build_nbr_kernel<<<N_NODES, 256, 0, stream>>>(adj, flag, cnt, nbr);
    conv_small_kernel<<<1, 256, 0, stream>>>(a1, a2, Wo, ao1, ao2, flag, smalls);
    wh_gemm_kernel<<<dim3(8, 64), 256, 0, stream>>>(X, W, flag, Whb);
    f12_kernel<<<128, 256, 0, stream>>>(Whb, a1c, a2c, f1, f2);
    attn1_kernel<<<N_NODES, 256, 0, stream>>>(Whb, f1, f2, cnt, nbr, catb);
    who_kernel<<<N_NODES / 16, 256, 0, stream>>>(catb, Woc, Who);
    g12_kernel<<<N_NODES / 256, 256, 0, stream>>>(Who, ao1c, ao2c, g1, g2);
    attn2_kernel<<<N_NODES, 64, 0, stream>>>(Who, g1, g2, cnt, nbr, flag, d_out);
}

// Round 8
// 198.446 us; speedup vs baseline: 1.3862x; 1.3862x over previous
//
#include <hip/hip_runtime.h>
#include <hip/hip_bf16.h>

#define N_NODES 4096
#define DIN     512
#define FDIM    64
#define NHEADS  8
#define DOUT    16
#define MAXN    512

typedef __attribute__((ext_vector_type(8))) short bf16x8;
typedef __attribute__((ext_vector_type(4))) float f32x4;

static __device__ __forceinline__ float us2f(unsigned short u) {
    union { unsigned int i; float f; } cv; cv.i = ((unsigned int)u) << 16; return cv.f;
}
static __device__ __forceinline__ unsigned short f2us(float v) {
    __hip_bfloat16 b = __float2bfloat16(v);
    return *(const unsigned short*)&b;
}

// K0: dtype detect (adj[0][0] is self-loop 1.0; fp32 low ushort = 0)
__global__ void detect_kernel(const unsigned short* __restrict__ adj, int* __restrict__ flag)
{
    if (threadIdx.x == 0) *flag = (adj[0] == 0) ? 1 : 0;
}

// K1: ROW-oriented neighbor lists (verified r4/r7)
__global__ __launch_bounds__(256) void build_nbr_kernel(
    const void* __restrict__ adj, const int* __restrict__ flag,
    int* __restrict__ cnt, int* __restrict__ nbr)
{
    const int n = blockIdx.x;
    const int f32 = *flag;
    __shared__ int c;
    if (threadIdx.x == 0) c = 0;
    __syncthreads();
    if (f32) {
        const unsigned int* row = (const unsigned int*)adj + (size_t)n * N_NODES;
        for (int m = threadIdx.x; m < N_NODES; m += 256) {
            if (row[m]) { int p = atomicAdd(&c, 1); if (p < MAXN) nbr[(size_t)n * MAXN + p] = m; }
        }
    } else {
        const unsigned short* row = (const unsigned short*)adj + (size_t)n * N_NODES;
        for (int m = threadIdx.x; m < N_NODES; m += 256) {
            if (row[m]) { int p = atomicAdd(&c, 1); if (p < MAXN) nbr[(size_t)n * MAXN + p] = m; }
        }
    }
    __syncthreads();
    if (threadIdx.x == 0) cnt[n] = (c < MAXN) ? c : MAXN;
}

// K2: small tensors -> canonical fp32: a1c[512]|a2c[512]|Woc[8192]|ao1c[16]|ao2c[16]
__global__ __launch_bounds__(256) void conv_small_kernel(
    const void* __restrict__ a1, const void* __restrict__ a2, const void* __restrict__ Wo,
    const void* __restrict__ ao1, const void* __restrict__ ao2,
    const int* __restrict__ flag, float* __restrict__ dst)
{
    const int f32 = *flag;
    const void* srcs[5] = { a1, a2, Wo, ao1, ao2 };
    const int   szs[5]  = { 512, 512, 8192, 16, 16 };
    int base = 0;
    for (int s = 0; s < 5; ++s) {
        if (f32) {
            for (int i = threadIdx.x; i < szs[s]; i += 256)
                dst[base + i] = ((const float*)srcs[s])[i];
        } else {
            for (int i = threadIdx.x; i < szs[s]; i += 256)
                dst[base + i] = us2f(((const unsigned short*)srcs[s])[i]);
        }
        base += szs[s];
    }
}

// ---------------------------------------------------------------------------
// K3 (NEW): MFMA GEMM Wh[h,n,f] = sum_d X[n,d] W[h,d,f].
// fp32 X split hi+lo bf16 (preserves X precision); W rounded to bf16.
// 64x64 tile/block, 4 waves, each wave 16 rows x 64 cols via 4 accs.
// LDS rows padded to 72 (144 B = 9*16B): 16B-aligned b128 reads, 2-way max.
// A-frag A[m=lane&15][k=quad*8+j]; B-frag = B^T rows (m91-verified gemm_bt);
// C/D col=lane&15, row=quad*4+reg (m89-verified).
// ---------------------------------------------------------------------------
__global__ __launch_bounds__(256) void wh_mfma_kernel(
    const void* __restrict__ X, const void* __restrict__ W,
    const int* __restrict__ flag, unsigned short* __restrict__ Whb)
{
    __shared__ unsigned short Ah[64][72];
    __shared__ unsigned short Al[64][72];
    __shared__ unsigned short Bt[64][72];
    const int f32 = *flag;
    const int h  = blockIdx.x;
    const int bm = blockIdx.y;
    const int tid  = threadIdx.x;
    const int w    = tid >> 6;
    const int lane = tid & 63;
    const int quad = lane >> 4;
    const int l16  = lane & 15;
    const int r  = tid >> 2;          // staging row 0..63
    const int c4 = (tid & 3) * 16;    // staging col base

    f32x4 acc[4];
#pragma unroll
    for (int j = 0; j < 4; ++j) acc[j] = (f32x4){0.f, 0.f, 0.f, 0.f};

    for (int k0 = 0; k0 < DIN; k0 += 64) {
        if (f32) {
            const float* xp = (const float*)X + (size_t)(bm * 64 + r) * DIN + k0 + c4;
            const float* wp = (const float*)W + (size_t)h * DIN * FDIM + (size_t)(k0 + r) * FDIM + c4;
#pragma unroll
            for (int i = 0; i < 16; ++i) {
                float v = xp[i];
                unsigned short hi = f2us(v);
                Ah[r][c4 + i] = hi;
                Al[r][c4 + i] = f2us(v - us2f(hi));
            }
#pragma unroll
            for (int i = 0; i < 16; ++i) Bt[c4 + i][r] = f2us(wp[i]);
        } else {
            const unsigned short* xp = (const unsigned short*)X + (size_t)(bm * 64 + r) * DIN + k0 + c4;
            const unsigned short* wp = (const unsigned short*)W + (size_t)h * DIN * FDIM + (size_t)(k0 + r) * FDIM + c4;
#pragma unroll
            for (int i = 0; i < 16; ++i) { Ah[r][c4 + i] = xp[i]; Al[r][c4 + i] = 0; }
#pragma unroll
            for (int i = 0; i < 16; ++i) Bt[c4 + i][r] = wp[i];
        }
        __syncthreads();
#pragma unroll
        for (int kk = 0; kk < 64; kk += 32) {
            bf16x8 a_hi = *(const bf16x8*)&Ah[w * 16 + l16][kk + quad * 8];
            bf16x8 a_lo = *(const bf16x8*)&Al[w * 16 + l16][kk + quad * 8];
#pragma unroll
            for (int j = 0; j < 4; ++j) {
                bf16x8 b = *(const bf16x8*)&Bt[j * 16 + l16][kk + quad * 8];
                acc[j] = __builtin_amdgcn_mfma_f32_16x16x32_bf16(a_hi, b, acc[j], 0, 0, 0);
                acc[j] = __builtin_amdgcn_mfma_f32_16x16x32_bf16(a_lo, b, acc[j], 0, 0, 0);
            }
        }
        __syncthreads();
    }
#pragma unroll
    for (int j = 0; j < 4; ++j) {
        int col = j * 16 + l16;
#pragma unroll
        for (int rr = 0; rr < 4; ++rr) {
            int row = bm * 64 + w * 16 + quad * 4 + rr;
            Whb[((size_t)h * N_NODES + row) * FDIM + col] = f2us(acc[j][rr]);
        }
    }
}

// K4: f1[h,n], f2[h,n]  (verified r4/r7)
__global__ __launch_bounds__(256) void f12_kernel(
    const unsigned short* __restrict__ Whb,
    const float* __restrict__ a1c, const float* __restrict__ a2c,
    float* __restrict__ f1, float* __restrict__ f2)
{
    int idx = blockIdx.x * 256 + threadIdx.x;
    int h = idx >> 12;
    const unsigned short* row = Whb + (size_t)idx * FDIM;
    float s1 = 0.f, s2 = 0.f;
#pragma unroll
    for (int f = 0; f < FDIM; ++f) {
        float v = us2f(row[f]);
        s1 += v * a1c[h * FDIM + f];
        s2 += v * a2c[h * FDIM + f];
    }
    f1[idx] = s1;
    f2[idx] = s2;
}

// K5: layer-1 sparse attention + ELU -> catb (verified r4/r7)
__global__ __launch_bounds__(256) void attn1_kernel(
    const unsigned short* __restrict__ Whb,
    const float* __restrict__ f1, const float* __restrict__ f2,
    const int* __restrict__ cnt, const int* __restrict__ nbr,
    unsigned short* __restrict__ catb)
{
    const int n = blockIdx.x;
    const int tid = threadIdx.x;
    const int wid = tid >> 6;
    const int lane = tid & 63;
    __shared__ int sh_m[MAXN];
    __shared__ float sh_s[4][MAXN];
    const int c0 = cnt[n];
    const int c = (c0 < MAXN) ? c0 : MAXN;
    for (int k = tid; k < c; k += 256) sh_m[k] = nbr[(size_t)n * MAXN + k];
    __syncthreads();
    for (int hh = 0; hh < 2; ++hh) {
        const int h = wid * 2 + hh;
        const float f1v = f1[h * N_NODES + n];
        float mx = -1e30f;
        for (int k = lane; k < c; k += 64) {
            float s = f1v + f2[h * N_NODES + sh_m[k]];
            s = (s >= 0.f) ? s : 0.2f * s;
            sh_s[wid][k] = s;
            mx = fmaxf(mx, s);
        }
#pragma unroll
        for (int off = 32; off; off >>= 1) mx = fmaxf(mx, __shfl_xor(mx, off));
        float sum = 0.f;
        for (int k = lane; k < c; k += 64) {
            float e = __expf(sh_s[wid][k] - mx);
            sh_s[wid][k] = e;
            sum += e;
        }
#pragma unroll
        for (int off = 32; off; off >>= 1) sum += __shfl_xor(sum, off);
        const float inv = (sum > 0.f) ? 1.f / sum : 0.f;
        float acc = 0.f;
        for (int k = 0; k < c; ++k)
            acc += sh_s[wid][k] * us2f(Whb[((size_t)h * N_NODES + sh_m[k]) * FDIM + lane]);
        acc *= inv;
        acc = (acc > 0.f) ? acc : expm1f(acc);
        catb[(size_t)n * (NHEADS * FDIM) + h * FDIM + lane] = f2us(acc);
        __syncthreads();
    }
}

// K6: Who = cat @ Wo  (verified r4/r7)
__global__ __launch_bounds__(256) void who_kernel(
    const unsigned short* __restrict__ catb, const float* __restrict__ Woc,
    float* __restrict__ Who)
{
    __shared__ float sWo[DIN * DOUT];
    for (int l = threadIdx.x; l < DIN * DOUT; l += 256) sWo[l] = Woc[l];
    __syncthreads();
    const int i = threadIdx.x >> 4;
    const int j = threadIdx.x & 15;
    const int n = blockIdx.x * 16 + i;
    const unsigned short* crow = catb + (size_t)n * DIN;
    float acc = 0.f;
    for (int d = 0; d < DIN; ++d) acc += us2f(crow[d]) * sWo[d * DOUT + j];
    Who[n * DOUT + j] = acc;
}

// K7: g1, g2  (verified r4/r7)
__global__ __launch_bounds__(256) void g12_kernel(
    const float* __restrict__ Who,
    const float* __restrict__ ao1c, const float* __restrict__ ao2c,
    float* __restrict__ g1, float* __restrict__ g2)
{
    int n = blockIdx.x * 256 + threadIdx.x;
    float s1 = 0.f, s2 = 0.f;
#pragma unroll
    for (int j = 0; j < DOUT; ++j) {
        float v = Who[n * DOUT + j];
        s1 += v * ao1c[j];
        s2 += v * ao2c[j];
    }
    g1[n] = s1;
    g2[n] = s2;
}

// K8: output sparse attention; fp32 store when fp32 inputs (verified r7)
__global__ __launch_bounds__(64) void attn2_kernel(
    const float* __restrict__ Who,
    const float* __restrict__ g1, const float* __restrict__ g2,
    const int* __restrict__ cnt, const int* __restrict__ nbr,
    const int* __restrict__ flag, void* __restrict__ out)
{
    const int n = blockIdx.x;
    const int lane = threadIdx.x;
    __shared__ float sh_s[MAXN];
    __shared__ int sh_m[MAXN];
    const int c0 = cnt[n];
    const int c = (c0 < MAXN) ? c0 : MAXN;
    for (int k = lane; k < c; k += 64) sh_m[k] = nbr[(size_t)n * MAXN + k];
    __syncthreads();
    const float gn = g1[n];
    float mx = -1e30f;
    for (int k = lane; k < c; k += 64) {
        float s = gn + g2[sh_m[k]];
        s = (s >= 0.f) ? s : 0.2f * s;
        sh_s[k] = s;
        mx = fmaxf(mx, s);
    }
#pragma unroll
    for (int off = 32; off; off >>= 1) mx = fmaxf(mx, __shfl_xor(mx, off));
    __syncthreads();
    float sum = 0.f;
    for (int k = lane; k < c; k += 64) {
        float e = __expf(sh_s[k] - mx);
        sh_s[k] = e;
        sum += e;
    }
#pragma unroll
    for (int off = 32; off; off >>= 1) sum += __shfl_xor(sum, off);
    __syncthreads();
    const float inv = (sum > 0.f) ? 1.f / sum : 0.f;
    if (lane < DOUT) {
        float acc = 0.f;
        for (int k = 0; k < c; ++k) acc += sh_s[k] * Who[sh_m[k] * DOUT + lane];
        acc *= inv;
        if (*flag) ((float*)out)[n * DOUT + lane] = acc;
        else       ((unsigned short*)out)[n * DOUT + lane] = f2us(acc);
    }
}

__global__ void wsfail_kernel(float* __restrict__ out)
{
    if (threadIdx.x == 0) out[0] = 129.f;
}

// ---------------------------------------------------------------------------
extern "C" void kernel_launch(void* const* d_in, const int* in_sizes, int n_in,
                              void* d_out, int out_size, void* d_ws, size_t ws_size,
                              hipStream_t stream)
{
    const void* adj = d_in[0];
    const void* X   = d_in[1];
    const void* W   = d_in[2];
    const void* a1  = d_in[3];
    const void* a2  = d_in[4];
    const void* Wo  = d_in[5];
    const void* ao1 = d_in[6];
    const void* ao2 = d_in[7];

    const size_t NEEDED = 17400000;   // verified available (r4..r7)
    if (ws_size < NEEDED) { wsfail_kernel<<<1, 64, 0, stream>>>((float*)d_out); return; }

    int* flag = (int*)d_ws;                         // 1
    int* cnt  = flag + 1;                           // 4096
    int* nbr  = cnt + 4096;                         // 4096*512
    float* smalls = (float*)(nbr + 2097152);        // 9248
    float* a1c  = smalls;
    float* a2c  = smalls + 512;
    float* Woc  = smalls + 1024;
    float* ao1c = smalls + 9216;
    float* ao2c = smalls + 9232;
    float* f1   = smalls + 9248;                    // 32768
    float* f2   = f1 + 32768;                       // 32768
    float* Who  = f2 + 32768;                       // 65536
    float* g1   = Who + 65536;                      // 4096
    float* g2   = g1 + 4096;                        // 4096
    unsigned short* Whb  = (unsigned short*)(g2 + 4096);  // 2097152 us
    unsigned short* catb = Whb + 2097152;                 // 2097152 us

    detect_kernel<<<1, 64, 0, stream>>>((const unsigned short*)adj, flag);
    build_nbr_kernel<<<N_NODES, 256, 0, stream>>>(adj, flag, cnt, nbr);
    conv_small_kernel<<<1, 256, 0, stream>>>(a1, a2, Wo, ao1, ao2, flag, smalls);
    wh_mfma_kernel<<<dim3(NHEADS, N_NODES / 64), 256, 0, stream>>>(X, W, flag, Whb);
    f12_kernel<<<128, 256, 0, stream>>>(Whb, a1c, a2c, f1, f2);
    attn1_kernel<<<N_NODES, 256, 0, stream>>>(Whb, f1, f2, cnt, nbr, catb);
    who_kernel<<<N_NODES / 16, 256, 0, stream>>>(catb, Woc, Who);
    g12_kernel<<<N_NODES / 256, 256, 0, stream>>>(Who, ao1c, ao2c, g1, g2);
    attn2_kernel<<<N_NODES, 64, 0, stream>>>(Who, g1, g2, cnt, nbr, flag, d_out);
}

// Round 9
// 183.665 us; speedup vs baseline: 1.4977x; 1.0805x over previous
//
#include <hip/hip_runtime.h>
#include <hip/hip_bf16.h>

#define N_NODES 4096
#define DIN     512
#define FDIM    64
#define NHEADS  8
#define DOUT    16
#define MAXN    512

typedef __attribute__((ext_vector_type(8))) short bf16x8;
typedef __attribute__((ext_vector_type(4))) float f32x4;

static __device__ __forceinline__ float us2f(unsigned short u) {
    union { unsigned int i; float f; } cv; cv.i = ((unsigned int)u) << 16; return cv.f;
}
static __device__ __forceinline__ unsigned short f2us(float v) {
    __hip_bfloat16 b = __float2bfloat16(v);
    return *(const unsigned short*)&b;
}

// ---------------------------------------------------------------------------
// K0: detect dtype + canonical small tensors + Wo^T hi/lo split (one block).
// smalls: a1c[512]|a2c[512]|Woc[8192]|ao1c[16]|ao2c[16]
// WtH/WtL: Wo^T as bf16 hi/lo, layout [col][d] (col<16, d<512)
// ---------------------------------------------------------------------------
__global__ __launch_bounds__(256) void setup_kernel(
    const void* __restrict__ adjv,
    const void* __restrict__ a1, const void* __restrict__ a2, const void* __restrict__ Wo,
    const void* __restrict__ ao1, const void* __restrict__ ao2,
    int* __restrict__ flag, float* __restrict__ dst,
    unsigned short* __restrict__ WtH, unsigned short* __restrict__ WtL)
{
    __shared__ int sflag;
    if (threadIdx.x == 0) {
        int f = (((const unsigned short*)adjv)[0] == 0) ? 1 : 0; // fp32 1.0 low-half = 0
        *flag = f;
        sflag = f;
    }
    __syncthreads();
    const int f32 = sflag;
    const void* srcs[5] = { a1, a2, Wo, ao1, ao2 };
    const int   szs[5]  = { 512, 512, 8192, 16, 16 };
    int base = 0;
    for (int s = 0; s < 5; ++s) {
        if (f32) {
            for (int i = threadIdx.x; i < szs[s]; i += 256)
                dst[base + i] = ((const float*)srcs[s])[i];
        } else {
            for (int i = threadIdx.x; i < szs[s]; i += 256)
                dst[base + i] = us2f(((const unsigned short*)srcs[s])[i]);
        }
        base += szs[s];
    }
    __syncthreads();   // Woc (dst[1024..9216)) visible to block
    const float* Woc = dst + 1024;
    for (int l = threadIdx.x; l < DIN * DOUT; l += 256) {
        int d = l >> 4, j = l & 15;
        float v = Woc[l];
        unsigned short hi = f2us(v);
        WtH[j * DIN + d] = hi;
        WtL[j * DIN + d] = f2us(v - us2f(hi));
    }
}

// ---------------------------------------------------------------------------
// K1: ROW-oriented neighbor lists (verified r7), vectorized scan.
// ---------------------------------------------------------------------------
__global__ __launch_bounds__(256) void build_nbr_kernel(
    const void* __restrict__ adj, const int* __restrict__ flag,
    int* __restrict__ cnt, int* __restrict__ nbr)
{
    const int n = blockIdx.x;
    const int f32 = *flag;
    __shared__ int c;
    if (threadIdx.x == 0) c = 0;
    __syncthreads();
    if (f32) {
        const uint4* row = (const uint4*)((const unsigned int*)adj + (size_t)n * N_NODES);
        for (int q = threadIdx.x; q < N_NODES / 4; q += 256) {
            uint4 v = row[q];
            int base = q * 4;
            if (v.x) { int p = atomicAdd(&c, 1); if (p < MAXN) nbr[(size_t)n * MAXN + p] = base + 0; }
            if (v.y) { int p = atomicAdd(&c, 1); if (p < MAXN) nbr[(size_t)n * MAXN + p] = base + 1; }
            if (v.z) { int p = atomicAdd(&c, 1); if (p < MAXN) nbr[(size_t)n * MAXN + p] = base + 2; }
            if (v.w) { int p = atomicAdd(&c, 1); if (p < MAXN) nbr[(size_t)n * MAXN + p] = base + 3; }
        }
    } else {
        const ushort4* row = (const ushort4*)((const unsigned short*)adj + (size_t)n * N_NODES);
        for (int q = threadIdx.x; q < N_NODES / 4; q += 256) {
            ushort4 v = row[q];
            int base = q * 4;
            if (v.x) { int p = atomicAdd(&c, 1); if (p < MAXN) nbr[(size_t)n * MAXN + p] = base + 0; }
            if (v.y) { int p = atomicAdd(&c, 1); if (p < MAXN) nbr[(size_t)n * MAXN + p] = base + 1; }
            if (v.z) { int p = atomicAdd(&c, 1); if (p < MAXN) nbr[(size_t)n * MAXN + p] = base + 2; }
            if (v.w) { int p = atomicAdd(&c, 1); if (p < MAXN) nbr[(size_t)n * MAXN + p] = base + 3; }
        }
    }
    __syncthreads();
    if (threadIdx.x == 0) cnt[n] = (c < MAXN) ? c : MAXN;
}

// ---------------------------------------------------------------------------
// K2: MFMA GEMM Wh[h,n,f] = sum_d X[n,d] W[h,d,f]  (verified r8).
// fp32 X split hi+lo bf16; W bf16. float4-vectorized staging.
// ---------------------------------------------------------------------------
__global__ __launch_bounds__(256) void wh_mfma_kernel(
    const void* __restrict__ X, const void* __restrict__ W,
    const int* __restrict__ flag, unsigned short* __restrict__ Whb)
{
    __shared__ unsigned short Ah[64][72];
    __shared__ unsigned short Al[64][72];
    __shared__ unsigned short Bt[64][72];
    const int f32 = *flag;
    const int h  = blockIdx.x;
    const int bm = blockIdx.y;
    const int tid  = threadIdx.x;
    const int w    = tid >> 6;
    const int lane = tid & 63;
    const int quad = lane >> 4;
    const int l16  = lane & 15;
    const int r  = tid >> 2;          // staging row 0..63
    const int c4 = (tid & 3) * 16;    // staging col base

    f32x4 acc[4];
#pragma unroll
    for (int j = 0; j < 4; ++j) acc[j] = (f32x4){0.f, 0.f, 0.f, 0.f};

    for (int k0 = 0; k0 < DIN; k0 += 64) {
        if (f32) {
            const float* xp = (const float*)X + (size_t)(bm * 64 + r) * DIN + k0 + c4;
            const float* wp = (const float*)W + (size_t)h * DIN * FDIM + (size_t)(k0 + r) * FDIM + c4;
#pragma unroll
            for (int i4 = 0; i4 < 4; ++i4) {
                float4 v4 = ((const float4*)xp)[i4];
                float vv[4] = { v4.x, v4.y, v4.z, v4.w };
#pragma unroll
                for (int t = 0; t < 4; ++t) {
                    int i = i4 * 4 + t;
                    unsigned short hi = f2us(vv[t]);
                    Ah[r][c4 + i] = hi;
                    Al[r][c4 + i] = f2us(vv[t] - us2f(hi));
                }
            }
#pragma unroll
            for (int i4 = 0; i4 < 4; ++i4) {
                float4 v4 = ((const float4*)wp)[i4];
                Bt[c4 + i4 * 4 + 0][r] = f2us(v4.x);
                Bt[c4 + i4 * 4 + 1][r] = f2us(v4.y);
                Bt[c4 + i4 * 4 + 2][r] = f2us(v4.z);
                Bt[c4 + i4 * 4 + 3][r] = f2us(v4.w);
            }
        } else {
            const unsigned short* xp = (const unsigned short*)X + (size_t)(bm * 64 + r) * DIN + k0 + c4;
            const unsigned short* wp = (const unsigned short*)W + (size_t)h * DIN * FDIM + (size_t)(k0 + r) * FDIM + c4;
#pragma unroll
            for (int i = 0; i < 16; ++i) { Ah[r][c4 + i] = xp[i]; Al[r][c4 + i] = 0; }
#pragma unroll
            for (int i = 0; i < 16; ++i) Bt[c4 + i][r] = wp[i];
        }
        __syncthreads();
#pragma unroll
        for (int kk = 0; kk < 64; kk += 32) {
            bf16x8 a_hi = *(const bf16x8*)&Ah[w * 16 + l16][kk + quad * 8];
            bf16x8 a_lo = *(const bf16x8*)&Al[w * 16 + l16][kk + quad * 8];
#pragma unroll
            for (int j = 0; j < 4; ++j) {
                bf16x8 b = *(const bf16x8*)&Bt[j * 16 + l16][kk + quad * 8];
                acc[j] = __builtin_amdgcn_mfma_f32_16x16x32_bf16(a_hi, b, acc[j], 0, 0, 0);
                acc[j] = __builtin_amdgcn_mfma_f32_16x16x32_bf16(a_lo, b, acc[j], 0, 0, 0);
            }
        }
        __syncthreads();
    }
#pragma unroll
    for (int j = 0; j < 4; ++j) {
        int col = j * 16 + l16;
#pragma unroll
        for (int rr = 0; rr < 4; ++rr) {
            int row = bm * 64 + w * 16 + quad * 4 + rr;
            Whb[((size_t)h * N_NODES + row) * FDIM + col] = f2us(acc[j][rr]);
        }
    }
}

// ---------------------------------------------------------------------------
// K3: f1[h,n], f2[h,n]; vectorized row loads; 128-thread blocks (256 blocks).
// ---------------------------------------------------------------------------
__global__ __launch_bounds__(128) void f12_kernel(
    const unsigned short* __restrict__ Whb,
    const float* __restrict__ a1c, const float* __restrict__ a2c,
    float* __restrict__ f1, float* __restrict__ f2)
{
    int idx = blockIdx.x * 128 + threadIdx.x;   // h*4096+n
    int h = idx >> 12;
    const bf16x8* row = (const bf16x8*)(Whb + (size_t)idx * FDIM);
    float s1 = 0.f, s2 = 0.f;
#pragma unroll
    for (int q = 0; q < 8; ++q) {
        bf16x8 v8 = row[q];
#pragma unroll
        for (int t = 0; t < 8; ++t) {
            float v = us2f((unsigned short)v8[t]);
            int f = q * 8 + t;
            s1 += v * a1c[h * FDIM + f];
            s2 += v * a2c[h * FDIM + f];
        }
    }
    f1[idx] = s1;
    f2[idx] = s2;
}

// ---------------------------------------------------------------------------
// K4: layer-1 sparse attention + ELU -> catb (verified r4/r7/r8)
// ---------------------------------------------------------------------------
__global__ __launch_bounds__(256) void attn1_kernel(
    const unsigned short* __restrict__ Whb,
    const float* __restrict__ f1, const float* __restrict__ f2,
    const int* __restrict__ cnt, const int* __restrict__ nbr,
    unsigned short* __restrict__ catb)
{
    const int n = blockIdx.x;
    const int tid = threadIdx.x;
    const int wid = tid >> 6;
    const int lane = tid & 63;
    __shared__ int sh_m[MAXN];
    __shared__ float sh_s[4][MAXN];
    const int c0 = cnt[n];
    const int c = (c0 < MAXN) ? c0 : MAXN;
    for (int k = tid; k < c; k += 256) sh_m[k] = nbr[(size_t)n * MAXN + k];
    __syncthreads();
    for (int hh = 0; hh < 2; ++hh) {
        const int h = wid * 2 + hh;
        const float f1v = f1[h * N_NODES + n];
        float mx = -1e30f;
        for (int k = lane; k < c; k += 64) {
            float s = f1v + f2[h * N_NODES + sh_m[k]];
            s = (s >= 0.f) ? s : 0.2f * s;
            sh_s[wid][k] = s;
            mx = fmaxf(mx, s);
        }
#pragma unroll
        for (int off = 32; off; off >>= 1) mx = fmaxf(mx, __shfl_xor(mx, off));
        float sum = 0.f;
        for (int k = lane; k < c; k += 64) {
            float e = __expf(sh_s[wid][k] - mx);
            sh_s[wid][k] = e;
            sum += e;
        }
#pragma unroll
        for (int off = 32; off; off >>= 1) sum += __shfl_xor(sum, off);
        const float inv = (sum > 0.f) ? 1.f / sum : 0.f;
        float acc = 0.f;
        for (int k = 0; k < c; ++k)
            acc += sh_s[wid][k] * us2f(Whb[((size_t)h * N_NODES + sh_m[k]) * FDIM + lane]);
        acc *= inv;
        acc = (acc > 0.f) ? acc : expm1f(acc);
        catb[(size_t)n * (NHEADS * FDIM) + h * FDIM + lane] = f2us(acc);
        __syncthreads();
    }
}

// ---------------------------------------------------------------------------
// K5 (NEW): Who = cat @ Wo via MFMA (hi+lo Wo), fused g1/g2.
// One wave per 16-row tile; B-frag from precomputed global Wo^T hi/lo.
// Fragment layouts identical to r8-verified wh_mfma (16x16x32 bf16).
// ---------------------------------------------------------------------------
__global__ __launch_bounds__(64) void who_mfma_g_kernel(
    const unsigned short* __restrict__ catb,
    const unsigned short* __restrict__ WtH, const unsigned short* __restrict__ WtL,
    const float* __restrict__ ao1c, const float* __restrict__ ao2c,
    float* __restrict__ Who, float* __restrict__ g1, float* __restrict__ g2)
{
    const int lane = threadIdx.x;
    const int quad = lane >> 4, l16 = lane & 15;
    const int row0 = blockIdx.x * 16;
    f32x4 acc = (f32x4){0.f, 0.f, 0.f, 0.f};
    for (int k0 = 0; k0 < DIN; k0 += 32) {
        bf16x8 a  = *(const bf16x8*)&catb[(size_t)(row0 + l16) * DIN + k0 + quad * 8];
        bf16x8 bh = *(const bf16x8*)&WtH[l16 * DIN + k0 + quad * 8];
        bf16x8 bl = *(const bf16x8*)&WtL[l16 * DIN + k0 + quad * 8];
        acc = __builtin_amdgcn_mfma_f32_16x16x32_bf16(a, bh, acc, 0, 0, 0);
        acc = __builtin_amdgcn_mfma_f32_16x16x32_bf16(a, bl, acc, 0, 0, 0);
    }
#pragma unroll
    for (int rr = 0; rr < 4; ++rr) {
        int row = row0 + quad * 4 + rr;
        float v = acc[rr];                      // Who[row][l16]
        Who[row * DOUT + l16] = v;
        float p1 = v * ao1c[l16];
        float p2 = v * ao2c[l16];
#pragma unroll
        for (int off = 8; off; off >>= 1) {     // reduce over l16 (within quad)
            p1 += __shfl_xor(p1, off);
            p2 += __shfl_xor(p2, off);
        }
        if (l16 == 0) { g1[row] = p1; g2[row] = p2; }
    }
}

// ---------------------------------------------------------------------------
// K6: output sparse attention; quad-parallel gather; fp32/bf16 store per flag.
// ---------------------------------------------------------------------------
__global__ __launch_bounds__(64) void attn2_kernel(
    const float* __restrict__ Who,
    const float* __restrict__ g1, const float* __restrict__ g2,
    const int* __restrict__ cnt, const int* __restrict__ nbr,
    const int* __restrict__ flag, void* __restrict__ out)
{
    const int n = blockIdx.x;
    const int lane = threadIdx.x;
    const int quad = lane >> 4, l16 = lane & 15;
    __shared__ float sh_s[MAXN];
    __shared__ int sh_m[MAXN];
    const int c0 = cnt[n];
    const int c = (c0 < MAXN) ? c0 : MAXN;
    for (int k = lane; k < c; k += 64) sh_m[k] = nbr[(size_t)n * MAXN + k];
    __syncthreads();
    const float gn = g1[n];
    float mx = -1e30f;
    for (int k = lane; k < c; k += 64) {
        float s = gn + g2[sh_m[k]];
        s = (s >= 0.f) ? s : 0.2f * s;
        sh_s[k] = s;
        mx = fmaxf(mx, s);
    }
#pragma unroll
    for (int off = 32; off; off >>= 1) mx = fmaxf(mx, __shfl_xor(mx, off));
    __syncthreads();
    float sum = 0.f;
    for (int k = lane; k < c; k += 64) {
        float e = __expf(sh_s[k] - mx);
        sh_s[k] = e;
        sum += e;
    }
#pragma unroll
    for (int off = 32; off; off >>= 1) sum += __shfl_xor(sum, off);
    __syncthreads();
    const float inv = (sum > 0.f) ? 1.f / sum : 0.f;
    float accv = 0.f;
    for (int k = quad; k < c; k += 4)
        accv += sh_s[k] * Who[sh_m[k] * DOUT + l16];
    accv += __shfl_xor(accv, 16);
    accv += __shfl_xor(accv, 32);
    if (quad == 0) {
        float v = accv * inv;
        if (*flag) ((float*)out)[n * DOUT + l16] = v;
        else       ((unsigned short*)out)[n * DOUT + l16] = f2us(v);
    }
}

__global__ void wsfail_kernel(float* __restrict__ out)
{
    if (threadIdx.x == 0) out[0] = 129.f;
}

// ---------------------------------------------------------------------------
extern "C" void kernel_launch(void* const* d_in, const int* in_sizes, int n_in,
                              void* d_out, int out_size, void* d_ws, size_t ws_size,
                              hipStream_t stream)
{
    const void* adj = d_in[0];
    const void* X   = d_in[1];
    const void* W   = d_in[2];
    const void* a1  = d_in[3];
    const void* a2  = d_in[4];
    const void* Wo  = d_in[5];
    const void* ao1 = d_in[6];
    const void* ao2 = d_in[7];

    const size_t NEEDED = 17500000;
    if (ws_size < NEEDED) { wsfail_kernel<<<1, 64, 0, stream>>>((float*)d_out); return; }

    int* flag = (int*)d_ws;                         // 1
    int* cnt  = flag + 1;                           // 4096
    int* nbr  = cnt + 4096;                         // 4096*512
    float* smalls = (float*)(nbr + 2097152);        // 9248
    float* a1c  = smalls;
    float* a2c  = smalls + 512;
    float* ao1c = smalls + 9216;
    float* ao2c = smalls + 9232;
    float* f1   = smalls + 9248;                    // 32768
    float* f2   = f1 + 32768;                       // 32768
    float* Who  = f2 + 32768;                       // 65536
    float* g1   = Who + 65536;                      // 4096
    float* g2   = g1 + 4096;                        // 4096
    unsigned short* Whb  = (unsigned short*)(g2 + 4096);  // 2097152 us
    unsigned short* catb = Whb + 2097152;                 // 2097152 us
    unsigned short* WtH  = catb + 2097152;                // 8192 us
    unsigned short* WtL  = WtH + 8192;                    // 8192 us

    setup_kernel<<<1, 256, 0, stream>>>(adj, a1, a2, Wo, ao1, ao2, flag, smalls, WtH, WtL);
    build_nbr_kernel<<<N_NODES, 256, 0, stream>>>(adj, flag, cnt, nbr);
    wh_mfma_kernel<<<dim3(NHEADS, N_NODES / 64), 256, 0, stream>>>(X, W, flag, Whb);
    f12_kernel<<<256, 128, 0, stream>>>(Whb, a1c, a2c, f1, f2);
    attn1_kernel<<<N_NODES, 256, 0, stream>>>(Whb, f1, f2, cnt, nbr, catb);
    who_mfma_g_kernel<<<N_NODES / 16, 64, 0, stream>>>(catb, WtH, WtL, ao1c, ao2c, Who, g1, g2);
    attn2_kernel<<<N_NODES, 64, 0, stream>>>(Who, g1, g2, cnt, nbr, flag, d_out);
}

// Round 10
// 177.436 us; speedup vs baseline: 1.5503x; 1.0351x over previous
//
#include <hip/hip_runtime.h>
#include <hip/hip_bf16.h>

#define N_NODES 4096
#define DIN     512
#define FDIM    64
#define NHEADS  8
#define DOUT    16
#define MAXN    512

typedef __attribute__((ext_vector_type(8))) short bf16x8;
typedef __attribute__((ext_vector_type(4))) float f32x4;

static __device__ __forceinline__ float us2f(unsigned short u) {
    union { unsigned int i; float f; } cv; cv.i = ((unsigned int)u) << 16; return cv.f;
}
static __device__ __forceinline__ unsigned short f2us(float v) {
    __hip_bfloat16 b = __float2bfloat16(v);
    return *(const unsigned short*)&b;
}
// dtype: adj[0][0] is a guaranteed self-loop 1.0; fp32 1.0f low ushort = 0 (verified r4-r9)
static __device__ __forceinline__ int is_f32(const void* adj) {
    return (((const unsigned short*)adj)[0] == 0) ? 1 : 0;
}

// ---------------------------------------------------------------------------
// K0: wide prep — Xhi/Xlo (hi+lo bf16 split of X), Wt[h][f][d] bf16,
// Wo^T hi/lo, small vecs fp32. Grid-stride, BW-bound.
// ---------------------------------------------------------------------------
__global__ __launch_bounds__(256) void prep_kernel(
    const void* __restrict__ adj, const void* __restrict__ X, const void* __restrict__ W,
    const void* __restrict__ a1, const void* __restrict__ a2, const void* __restrict__ Wo,
    const void* __restrict__ ao1, const void* __restrict__ ao2,
    unsigned short* __restrict__ Xhi, unsigned short* __restrict__ Xlo,
    unsigned short* __restrict__ Wt,
    unsigned short* __restrict__ WtH, unsigned short* __restrict__ WtL,
    float* __restrict__ a1c, float* __restrict__ a2c,
    float* __restrict__ ao1c, float* __restrict__ ao2c)
{
    const int f32 = is_f32(adj);
    const int i0 = blockIdx.x * 256 + threadIdx.x;
    const int T = gridDim.x * 256;
    // X -> hi/lo split (bf16 input: hi = value, lo = 0 automatically)
    for (int i = i0; i < N_NODES * DIN; i += T) {
        float v = f32 ? ((const float*)X)[i] : us2f(((const unsigned short*)X)[i]);
        unsigned short hi = f2us(v);
        Xhi[i] = hi;
        Xlo[i] = f2us(v - us2f(hi));
    }
    // W[h][d][f] -> Wt[h][f][d] (B-fragment major)
    for (int i = i0; i < NHEADS * DIN * FDIM; i += T) {
        int hh = i >> 15, rem = i & 32767, d = rem >> 6, f = rem & 63;
        float v = f32 ? ((const float*)W)[i] : us2f(((const unsigned short*)W)[i]);
        Wt[((size_t)(hh * FDIM + f)) * DIN + d] = f2us(v);
    }
    // Wo[d][j] -> WtH/WtL[j][d] hi+lo
    for (int i = i0; i < DIN * DOUT; i += T) {
        int d = i >> 4, j = i & 15;
        float v = f32 ? ((const float*)Wo)[i] : us2f(((const unsigned short*)Wo)[i]);
        unsigned short hi = f2us(v);
        WtH[j * DIN + d] = hi;
        WtL[j * DIN + d] = f2us(v - us2f(hi));
    }
    if (i0 < 512) {
        a1c[i0] = f32 ? ((const float*)a1)[i0] : us2f(((const unsigned short*)a1)[i0]);
        a2c[i0] = f32 ? ((const float*)a2)[i0] : us2f(((const unsigned short*)a2)[i0]);
    }
    if (i0 < 16) {
        ao1c[i0] = f32 ? ((const float*)ao1)[i0] : us2f(((const unsigned short*)ao1)[i0]);
        ao2c[i0] = f32 ? ((const float*)ao2)[i0] : us2f(((const unsigned short*)ao2)[i0]);
    }
}

// ---------------------------------------------------------------------------
// K1: ROW-oriented neighbor lists (verified r7-r9), vectorized scan.
// ---------------------------------------------------------------------------
__global__ __launch_bounds__(256) void build_nbr_kernel(
    const void* __restrict__ adj, int* __restrict__ cnt, int* __restrict__ nbr)
{
    const int n = blockIdx.x;
    const int f32 = is_f32(adj);
    __shared__ int c;
    if (threadIdx.x == 0) c = 0;
    __syncthreads();
    if (f32) {
        const uint4* row = (const uint4*)((const unsigned int*)adj + (size_t)n * N_NODES);
        for (int q = threadIdx.x; q < N_NODES / 4; q += 256) {
            uint4 v = row[q];
            int base = q * 4;
            if (v.x) { int p = atomicAdd(&c, 1); if (p < MAXN) nbr[(size_t)n * MAXN + p] = base + 0; }
            if (v.y) { int p = atomicAdd(&c, 1); if (p < MAXN) nbr[(size_t)n * MAXN + p] = base + 1; }
            if (v.z) { int p = atomicAdd(&c, 1); if (p < MAXN) nbr[(size_t)n * MAXN + p] = base + 2; }
            if (v.w) { int p = atomicAdd(&c, 1); if (p < MAXN) nbr[(size_t)n * MAXN + p] = base + 3; }
        }
    } else {
        const ushort4* row = (const ushort4*)((const unsigned short*)adj + (size_t)n * N_NODES);
        for (int q = threadIdx.x; q < N_NODES / 4; q += 256) {
            ushort4 v = row[q];
            int base = q * 4;
            if (v.x) { int p = atomicAdd(&c, 1); if (p < MAXN) nbr[(size_t)n * MAXN + p] = base + 0; }
            if (v.y) { int p = atomicAdd(&c, 1); if (p < MAXN) nbr[(size_t)n * MAXN + p] = base + 1; }
            if (v.z) { int p = atomicAdd(&c, 1); if (p < MAXN) nbr[(size_t)n * MAXN + p] = base + 2; }
            if (v.w) { int p = atomicAdd(&c, 1); if (p < MAXN) nbr[(size_t)n * MAXN + p] = base + 3; }
        }
    }
    __syncthreads();
    if (threadIdx.x == 0) cnt[n] = (c < MAXN) ? c : MAXN;
}

// ---------------------------------------------------------------------------
// K2: MFMA GEMM, fragments straight from global (no LDS, no barriers).
// Wh[n][h][f] = sum_d X[n,d] W[h,d,f]. A = Xhi/Xlo rows; B = Wt[h][f][d] rows.
// Fragment layouts identical to r8/r9-verified kernels (16x16x32 bf16).
// NEW Whb layout: [n][h][f] (one node's 8 heads contiguous, 1 KB).
// ---------------------------------------------------------------------------
__global__ __launch_bounds__(256) void wh_mfma_kernel(
    const unsigned short* __restrict__ Xhi, const unsigned short* __restrict__ Xlo,
    const unsigned short* __restrict__ Wt, unsigned short* __restrict__ Whb)
{
    const int h  = blockIdx.x;
    const int bm = blockIdx.y;
    const int w    = threadIdx.x >> 6;
    const int lane = threadIdx.x & 63;
    const int quad = lane >> 4;
    const int l16  = lane & 15;
    const int rowA = bm * 64 + w * 16 + l16;

    f32x4 acc[4];
#pragma unroll
    for (int j = 0; j < 4; ++j) acc[j] = (f32x4){0.f, 0.f, 0.f, 0.f};

    const unsigned short* xh = Xhi + (size_t)rowA * DIN + quad * 8;
    const unsigned short* xl = Xlo + (size_t)rowA * DIN + quad * 8;
    const unsigned short* wb = Wt + (size_t)h * FDIM * DIN + quad * 8;
#pragma unroll 2
    for (int k0 = 0; k0 < DIN; k0 += 32) {
        bf16x8 ah = *(const bf16x8*)(xh + k0);
        bf16x8 al = *(const bf16x8*)(xl + k0);
#pragma unroll
        for (int j = 0; j < 4; ++j) {
            bf16x8 b = *(const bf16x8*)(wb + (size_t)(j * 16 + l16) * DIN + k0);
            acc[j] = __builtin_amdgcn_mfma_f32_16x16x32_bf16(ah, b, acc[j], 0, 0, 0);
            acc[j] = __builtin_amdgcn_mfma_f32_16x16x32_bf16(al, b, acc[j], 0, 0, 0);
        }
    }
#pragma unroll
    for (int j = 0; j < 4; ++j) {
        int col = j * 16 + l16;
#pragma unroll
        for (int rr = 0; rr < 4; ++rr) {
            int row = bm * 64 + w * 16 + quad * 4 + rr;
            Whb[((size_t)row * NHEADS + h) * FDIM + col] = f2us(acc[j][rr]);
        }
    }
}

// ---------------------------------------------------------------------------
// K3: f1[h][n], f2[h][n] from Whb[n][h][f]; idx = n*8+h -> fully coalesced rows.
// a-vecs staged to LDS in [f*8+h] order (conflict-free broadcast).
// ---------------------------------------------------------------------------
__global__ __launch_bounds__(256) void f12_kernel(
    const unsigned short* __restrict__ Whb,
    const float* __restrict__ a1c, const float* __restrict__ a2c,
    float* __restrict__ f1, float* __restrict__ f2)
{
    __shared__ float sA1[512], sA2[512];
    for (int i = threadIdx.x; i < 512; i += 256) {
        int hh = i & 7, ff = i >> 3;
        sA1[i] = a1c[hh * FDIM + ff];
        sA2[i] = a2c[hh * FDIM + ff];
    }
    __syncthreads();
    int idx = blockIdx.x * 256 + threadIdx.x;   // n*8+h
    int h = idx & 7, n = idx >> 3;
    const bf16x8* row = (const bf16x8*)(Whb + (size_t)idx * FDIM);
    float s1 = 0.f, s2 = 0.f;
#pragma unroll
    for (int q = 0; q < 8; ++q) {
        bf16x8 v8 = row[q];
#pragma unroll
        for (int t = 0; t < 8; ++t) {
            float v = us2f((unsigned short)v8[t]);
            int f = q * 8 + t;
            s1 += v * sA1[f * 8 + h];
            s2 += v * sA2[f * 8 + h];
        }
    }
    f1[h * N_NODES + n] = s1;
    f2[h * N_NODES + n] = s2;
}

// ---------------------------------------------------------------------------
// K4: layer-1 attention, ALL 8 HEADS in one pass per node (Whb[n][h][f]).
// Scores: thread group h=tid>>5 (32 lanes/head). Gather: per k one coalesced
// 1 KB row load; thread handles 2 elements (e=2*tid, h = tid>>5 matches).
// ---------------------------------------------------------------------------
__global__ __launch_bounds__(256) void attn1_kernel(
    const unsigned short* __restrict__ Whb,
    const float* __restrict__ f1, const float* __restrict__ f2,
    const int* __restrict__ cnt, const int* __restrict__ nbr,
    unsigned short* __restrict__ catb)
{
    const int n = blockIdx.x;
    const int tid = threadIdx.x;
    __shared__ int sh_m[MAXN];
    __shared__ float sh_s[NHEADS][MAXN];
    __shared__ float sh_inv[NHEADS];
    const int c0 = cnt[n];
    const int c = (c0 < MAXN) ? c0 : MAXN;
    for (int k = tid; k < c; k += 256) sh_m[k] = nbr[(size_t)n * MAXN + k];
    __syncthreads();
    const int h = tid >> 5;
    const int l32 = tid & 31;
    const float f1v = f1[h * N_NODES + n];
    float mx = -1e30f;
    for (int k = l32; k < c; k += 32) {
        float s = f1v + f2[h * N_NODES + sh_m[k]];
        s = (s >= 0.f) ? s : 0.2f * s;              // LeakyReLU(0.2)
        sh_s[h][k] = s;
        mx = fmaxf(mx, s);
    }
#pragma unroll
    for (int off = 16; off; off >>= 1) mx = fmaxf(mx, __shfl_xor(mx, off));
    __syncthreads();
    float sum = 0.f;
    for (int k = l32; k < c; k += 32) {
        float e = __expf(sh_s[h][k] - mx);
        sh_s[h][k] = e;
        sum += e;
    }
#pragma unroll
    for (int off = 16; off; off >>= 1) sum += __shfl_xor(sum, off);
    if (l32 == 0) sh_inv[h] = (sum > 0.f) ? 1.f / sum : 0.f;
    __syncthreads();
    // gather: elements e = 2*tid, 2*tid+1 (same h = tid>>5); per k: 1 KB block load
    float a0 = 0.f, a1v = 0.f;
    const unsigned int* base = (const unsigned int*)Whb;  // 2 bf16 per uint
#pragma unroll 4
    for (int k = 0; k < c; ++k) {
        unsigned int u = base[(size_t)sh_m[k] * 256 + tid];
        float wgt = sh_s[h][k];
        a0  += wgt * us2f((unsigned short)(u & 0xFFFFu));
        a1v += wgt * us2f((unsigned short)(u >> 16));
    }
    const float inv = sh_inv[h];
    a0 *= inv; a1v *= inv;
    a0  = (a0  > 0.f) ? a0  : expm1f(a0);           // ELU
    a1v = (a1v > 0.f) ? a1v : expm1f(a1v);
    unsigned int o = (unsigned int)f2us(a0) | ((unsigned int)f2us(a1v) << 16);
    ((unsigned int*)catb)[(size_t)n * 256 + tid] = o;
}

// ---------------------------------------------------------------------------
// K5: Who = cat @ Wo via MFMA (hi+lo Wo), fused g1/g2 (verified r9).
// ---------------------------------------------------------------------------
__global__ __launch_bounds__(64) void who_mfma_g_kernel(
    const unsigned short* __restrict__ catb,
    const unsigned short* __restrict__ WtH, const unsigned short* __restrict__ WtL,
    const float* __restrict__ ao1c, const float* __restrict__ ao2c,
    float* __restrict__ Who, float* __restrict__ g1, float* __restrict__ g2)
{
    const int lane = threadIdx.x;
    const int quad = lane >> 4, l16 = lane & 15;
    const int row0 = blockIdx.x * 16;
    f32x4 acc = (f32x4){0.f, 0.f, 0.f, 0.f};
    for (int k0 = 0; k0 < DIN; k0 += 32) {
        bf16x8 a  = *(const bf16x8*)&catb[(size_t)(row0 + l16) * DIN + k0 + quad * 8];
        bf16x8 bh = *(const bf16x8*)&WtH[l16 * DIN + k0 + quad * 8];
        bf16x8 bl = *(const bf16x8*)&WtL[l16 * DIN + k0 + quad * 8];
        acc = __builtin_amdgcn_mfma_f32_16x16x32_bf16(a, bh, acc, 0, 0, 0);
        acc = __builtin_amdgcn_mfma_f32_16x16x32_bf16(a, bl, acc, 0, 0, 0);
    }
#pragma unroll
    for (int rr = 0; rr < 4; ++rr) {
        int row = row0 + quad * 4 + rr;
        float v = acc[rr];
        Who[row * DOUT + l16] = v;
        float p1 = v * ao1c[l16];
        float p2 = v * ao2c[l16];
#pragma unroll
        for (int off = 8; off; off >>= 1) {
            p1 += __shfl_xor(p1, off);
            p2 += __shfl_xor(p2, off);
        }
        if (l16 == 0) { g1[row] = p1; g2[row] = p2; }
    }
}

// ---------------------------------------------------------------------------
// K6: output sparse attention (verified r9); fp32/bf16 store per dtype.
// ---------------------------------------------------------------------------
__global__ __launch_bounds__(64) void attn2_kernel(
    const void* __restrict__ adj,
    const float* __restrict__ Who,
    const float* __restrict__ g1, const float* __restrict__ g2,
    const int* __restrict__ cnt, const int* __restrict__ nbr,
    void* __restrict__ out)
{
    const int n = blockIdx.x;
    const int lane = threadIdx.x;
    const int quad = lane >> 4, l16 = lane & 15;
    __shared__ float sh_s[MAXN];
    __shared__ int sh_m[MAXN];
    const int c0 = cnt[n];
    const int c = (c0 < MAXN) ? c0 : MAXN;
    for (int k = lane; k < c; k += 64) sh_m[k] = nbr[(size_t)n * MAXN + k];
    __syncthreads();
    const float gn = g1[n];
    float mx = -1e30f;
    for (int k = lane; k < c; k += 64) {
        float s = gn + g2[sh_m[k]];
        s = (s >= 0.f) ? s : 0.2f * s;
        sh_s[k] = s;
        mx = fmaxf(mx, s);
    }
#pragma unroll
    for (int off = 32; off; off >>= 1) mx = fmaxf(mx, __shfl_xor(mx, off));
    __syncthreads();
    float sum = 0.f;
    for (int k = lane; k < c; k += 64) {
        float e = __expf(sh_s[k] - mx);
        sh_s[k] = e;
        sum += e;
    }
#pragma unroll
    for (int off = 32; off; off >>= 1) sum += __shfl_xor(sum, off);
    __syncthreads();
    const float inv = (sum > 0.f) ? 1.f / sum : 0.f;
    float accv = 0.f;
    for (int k = quad; k < c; k += 4)
        accv += sh_s[k] * Who[sh_m[k] * DOUT + l16];
    accv += __shfl_xor(accv, 16);
    accv += __shfl_xor(accv, 32);
    if (quad == 0) {
        float v = accv * inv;
        if (is_f32(adj)) ((float*)out)[n * DOUT + l16] = v;
        else             ((unsigned short*)out)[n * DOUT + l16] = f2us(v);
    }
}

__global__ void wsfail_kernel(float* __restrict__ out)
{
    if (threadIdx.x == 0) out[0] = 129.f;
}

// ---------------------------------------------------------------------------
extern "C" void kernel_launch(void* const* d_in, const int* in_sizes, int n_in,
                              void* d_out, int out_size, void* d_ws, size_t ws_size,
                              hipStream_t stream)
{
    const void* adj = d_in[0];
    const void* X   = d_in[1];
    const void* W   = d_in[2];
    const void* a1  = d_in[3];
    const void* a2  = d_in[4];
    const void* Wo  = d_in[5];
    const void* ao1 = d_in[6];
    const void* ao2 = d_in[7];

    const size_t NEEDED = 26400000;
    if (ws_size < NEEDED) { wsfail_kernel<<<1, 64, 0, stream>>>((float*)d_out); return; }

    int*   cnt  = (int*)d_ws;                        // 4096
    int*   nbr  = cnt + 4096;                        // 4096*512
    float* a1c  = (float*)(nbr + 2097152);           // 512
    float* a2c  = a1c + 512;                         // 512
    float* ao1c = a2c + 512;                         // 16
    float* ao2c = ao1c + 16;                         // 16
    float* f1   = ao2c + 16;                         // 32768
    float* f2   = f1 + 32768;                        // 32768
    float* Who  = f2 + 32768;                        // 65536
    float* g1   = Who + 65536;                       // 4096
    float* g2   = g1 + 4096;                         // 4096
    unsigned short* Whb  = (unsigned short*)(g2 + 4096);  // 2097152
    unsigned short* catb = Whb + 2097152;                 // 2097152
    unsigned short* Xhi  = catb + 2097152;                // 2097152
    unsigned short* Xlo  = Xhi + 2097152;                 // 2097152
    unsigned short* Wt   = Xlo + 2097152;                 // 262144
    unsigned short* WtH  = Wt + 262144;                   // 8192
    unsigned short* WtL  = WtH + 8192;                    // 8192

    prep_kernel<<<1024, 256, 0, stream>>>(adj, X, W, a1, a2, Wo, ao1, ao2,
                                          Xhi, Xlo, Wt, WtH, WtL, a1c, a2c, ao1c, ao2c);
    build_nbr_kernel<<<N_NODES, 256, 0, stream>>>(adj, cnt, nbr);
    wh_mfma_kernel<<<dim3(NHEADS, N_NODES / 64), 256, 0, stream>>>(Xhi, Xlo, Wt, Whb);
    f12_kernel<<<128, 256, 0, stream>>>(Whb, a1c, a2c, f1, f2);
    attn1_kernel<<<N_NODES, 256, 0, stream>>>(Whb, f1, f2, cnt, nbr, catb);
    who_mfma_g_kernel<<<N_NODES / 16, 64, 0, stream>>>(catb, WtH, WtL, ao1c, ao2c, Who, g1, g2);
    attn2_kernel<<<N_NODES, 64, 0, stream>>>(adj, Who, g1, g2, cnt, nbr, d_out);
}

// Round 11
// 165.385 us; speedup vs baseline: 1.6633x; 1.0729x over previous
//
#include <hip/hip_runtime.h>
#include <hip/hip_bf16.h>

#define N_NODES 4096
#define DIN     512
#define FDIM    64
#define NHEADS  8
#define DOUT    16
#define MAXN    512

typedef __attribute__((ext_vector_type(8))) short bf16x8;
typedef __attribute__((ext_vector_type(4))) float f32x4;

static __device__ __forceinline__ float us2f(unsigned short u) {
    union { unsigned int i; float f; } cv; cv.i = ((unsigned int)u) << 16; return cv.f;
}
static __device__ __forceinline__ unsigned short f2us(float v) {
    __hip_bfloat16 b = __float2bfloat16(v);
    return *(const unsigned short*)&b;
}
// dtype: adj[0][0] is a guaranteed self-loop 1.0; fp32 1.0f low ushort = 0 (verified r4-r10)
static __device__ __forceinline__ int is_f32(const void* adj) {
    return (((const unsigned short*)adj)[0] == 0) ? 1 : 0;
}

// ---------------------------------------------------------------------------
// K0: prep (blocks 0..1023) + row neighbor lists (blocks 1024..5119) merged.
// prep: Xhi/Xlo hi+lo bf16 split, Wt[h][f][d] bf16, Wo^T hi/lo, small vecs.
// ---------------------------------------------------------------------------
__global__ __launch_bounds__(256) void prep_nbr_kernel(
    const void* __restrict__ adj, const void* __restrict__ X, const void* __restrict__ W,
    const void* __restrict__ a1, const void* __restrict__ a2, const void* __restrict__ Wo,
    const void* __restrict__ ao1, const void* __restrict__ ao2,
    unsigned short* __restrict__ Xhi, unsigned short* __restrict__ Xlo,
    unsigned short* __restrict__ Wt,
    unsigned short* __restrict__ WtH, unsigned short* __restrict__ WtL,
    float* __restrict__ a1c, float* __restrict__ a2c,
    float* __restrict__ ao1c, float* __restrict__ ao2c,
    int* __restrict__ cnt, int* __restrict__ nbr)
{
    const int f32 = is_f32(adj);
    if (blockIdx.x >= 1024) {
        // ---- neighbor list for node n (verified r7-r10) ----
        const int n = blockIdx.x - 1024;
        __shared__ int c;
        if (threadIdx.x == 0) c = 0;
        __syncthreads();
        if (f32) {
            const uint4* row = (const uint4*)((const unsigned int*)adj + (size_t)n * N_NODES);
            for (int q = threadIdx.x; q < N_NODES / 4; q += 256) {
                uint4 v = row[q];
                int base = q * 4;
                if (v.x) { int p = atomicAdd(&c, 1); if (p < MAXN) nbr[(size_t)n * MAXN + p] = base + 0; }
                if (v.y) { int p = atomicAdd(&c, 1); if (p < MAXN) nbr[(size_t)n * MAXN + p] = base + 1; }
                if (v.z) { int p = atomicAdd(&c, 1); if (p < MAXN) nbr[(size_t)n * MAXN + p] = base + 2; }
                if (v.w) { int p = atomicAdd(&c, 1); if (p < MAXN) nbr[(size_t)n * MAXN + p] = base + 3; }
            }
        } else {
            const ushort4* row = (const ushort4*)((const unsigned short*)adj + (size_t)n * N_NODES);
            for (int q = threadIdx.x; q < N_NODES / 4; q += 256) {
                ushort4 v = row[q];
                int base = q * 4;
                if (v.x) { int p = atomicAdd(&c, 1); if (p < MAXN) nbr[(size_t)n * MAXN + p] = base + 0; }
                if (v.y) { int p = atomicAdd(&c, 1); if (p < MAXN) nbr[(size_t)n * MAXN + p] = base + 1; }
                if (v.z) { int p = atomicAdd(&c, 1); if (p < MAXN) nbr[(size_t)n * MAXN + p] = base + 2; }
                if (v.w) { int p = atomicAdd(&c, 1); if (p < MAXN) nbr[(size_t)n * MAXN + p] = base + 3; }
            }
        }
        __syncthreads();
        if (threadIdx.x == 0) cnt[n] = (c < MAXN) ? c : MAXN;
        return;
    }
    // ---- prep (blocks 0..1023) ----
    const int i0 = blockIdx.x * 256 + threadIdx.x;
    const int T = 1024 * 256;
    for (int i = i0; i < N_NODES * DIN; i += T) {
        float v = f32 ? ((const float*)X)[i] : us2f(((const unsigned short*)X)[i]);
        unsigned short hi = f2us(v);
        Xhi[i] = hi;
        Xlo[i] = f2us(v - us2f(hi));
    }
    for (int i = i0; i < NHEADS * DIN * FDIM; i += T) {
        int hh = i >> 15, rem = i & 32767, d = rem >> 6, f = rem & 63;
        float v = f32 ? ((const float*)W)[i] : us2f(((const unsigned short*)W)[i]);
        Wt[((size_t)(hh * FDIM + f)) * DIN + d] = f2us(v);
    }
    for (int i = i0; i < DIN * DOUT; i += T) {
        int d = i >> 4, j = i & 15;
        float v = f32 ? ((const float*)Wo)[i] : us2f(((const unsigned short*)Wo)[i]);
        unsigned short hi = f2us(v);
        WtH[j * DIN + d] = hi;
        WtL[j * DIN + d] = f2us(v - us2f(hi));
    }
    if (i0 < 512) {
        a1c[i0] = f32 ? ((const float*)a1)[i0] : us2f(((const unsigned short*)a1)[i0]);
        a2c[i0] = f32 ? ((const float*)a2)[i0] : us2f(((const unsigned short*)a2)[i0]);
    }
    if (i0 < 16) {
        ao1c[i0] = f32 ? ((const float*)ao1)[i0] : us2f(((const unsigned short*)ao1)[i0]);
        ao2c[i0] = f32 ? ((const float*)ao2)[i0] : us2f(((const unsigned short*)ao2)[i0]);
    }
}

// ---------------------------------------------------------------------------
// K1: MFMA GEMM (fragments from global, no LDS/barriers — verified r10)
// + FUSED f1/f2: per-lane dot of fp32 acc with a1/a2 cols, 16-lane shfl reduce.
// Whb layout [n][h][f] (verified r10).
// ---------------------------------------------------------------------------
__global__ __launch_bounds__(256) void wh_f12_kernel(
    const unsigned short* __restrict__ Xhi, const unsigned short* __restrict__ Xlo,
    const unsigned short* __restrict__ Wt,
    const float* __restrict__ a1c, const float* __restrict__ a2c,
    unsigned short* __restrict__ Whb, float* __restrict__ f1, float* __restrict__ f2)
{
    const int h  = blockIdx.x;
    const int bm = blockIdx.y;
    const int w    = threadIdx.x >> 6;
    const int lane = threadIdx.x & 63;
    const int quad = lane >> 4;
    const int l16  = lane & 15;
    const int rowA = bm * 64 + w * 16 + l16;

    f32x4 acc[4];
#pragma unroll
    for (int j = 0; j < 4; ++j) acc[j] = (f32x4){0.f, 0.f, 0.f, 0.f};

    const unsigned short* xh = Xhi + (size_t)rowA * DIN + quad * 8;
    const unsigned short* xl = Xlo + (size_t)rowA * DIN + quad * 8;
    const unsigned short* wb = Wt + (size_t)h * FDIM * DIN + quad * 8;
#pragma unroll 2
    for (int k0 = 0; k0 < DIN; k0 += 32) {
        bf16x8 ah = *(const bf16x8*)(xh + k0);
        bf16x8 al = *(const bf16x8*)(xl + k0);
#pragma unroll
        for (int j = 0; j < 4; ++j) {
            bf16x8 b = *(const bf16x8*)(wb + (size_t)(j * 16 + l16) * DIN + k0);
            acc[j] = __builtin_amdgcn_mfma_f32_16x16x32_bf16(ah, b, acc[j], 0, 0, 0);
            acc[j] = __builtin_amdgcn_mfma_f32_16x16x32_bf16(al, b, acc[j], 0, 0, 0);
        }
    }
    // store Wh (bf16) and fused f1/f2 from fp32 accs
    float av1[4], av2[4];
#pragma unroll
    for (int j = 0; j < 4; ++j) {
        int col = j * 16 + l16;
        av1[j] = a1c[h * FDIM + col];
        av2[j] = a2c[h * FDIM + col];
#pragma unroll
        for (int rr = 0; rr < 4; ++rr) {
            int row = bm * 64 + w * 16 + quad * 4 + rr;
            Whb[((size_t)row * NHEADS + h) * FDIM + col] = f2us(acc[j][rr]);
        }
    }
#pragma unroll
    for (int rr = 0; rr < 4; ++rr) {
        float p1 = acc[0][rr] * av1[0] + acc[1][rr] * av1[1] + acc[2][rr] * av1[2] + acc[3][rr] * av1[3];
        float p2 = acc[0][rr] * av2[0] + acc[1][rr] * av2[1] + acc[2][rr] * av2[2] + acc[3][rr] * av2[3];
#pragma unroll
        for (int off = 8; off; off >>= 1) {   // reduce over the 16 l16 lanes
            p1 += __shfl_xor(p1, off);
            p2 += __shfl_xor(p2, off);
        }
        if (l16 == 0) {
            int row = bm * 64 + w * 16 + quad * 4 + rr;
            f1[h * N_NODES + row] = p1;
            f2[h * N_NODES + row] = p2;
        }
    }
}

// ---------------------------------------------------------------------------
// K2: layer-1 attention, all 8 heads per node (verified r10).
// sh_s padded to 516: head stride ≡ 4 mod 32 → 8 heads on 8 distinct banks.
// ---------------------------------------------------------------------------
__global__ __launch_bounds__(256) void attn1_kernel(
    const unsigned short* __restrict__ Whb,
    const float* __restrict__ f1, const float* __restrict__ f2,
    const int* __restrict__ cnt, const int* __restrict__ nbr,
    unsigned short* __restrict__ catb)
{
    const int n = blockIdx.x;
    const int tid = threadIdx.x;
    __shared__ int sh_m[MAXN];
    __shared__ float sh_s[NHEADS][516];
    __shared__ float sh_inv[NHEADS];
    const int c0 = cnt[n];
    const int c = (c0 < MAXN) ? c0 : MAXN;
    for (int k = tid; k < c; k += 256) sh_m[k] = nbr[(size_t)n * MAXN + k];
    __syncthreads();
    const int h = tid >> 5;
    const int l32 = tid & 31;
    const float f1v = f1[h * N_NODES + n];
    float mx = -1e30f;
    for (int k = l32; k < c; k += 32) {
        float s = f1v + f2[h * N_NODES + sh_m[k]];
        s = (s >= 0.f) ? s : 0.2f * s;              // LeakyReLU(0.2)
        sh_s[h][k] = s;
        mx = fmaxf(mx, s);
    }
#pragma unroll
    for (int off = 16; off; off >>= 1) mx = fmaxf(mx, __shfl_xor(mx, off));
    __syncthreads();
    float sum = 0.f;
    for (int k = l32; k < c; k += 32) {
        float e = __expf(sh_s[h][k] - mx);
        sh_s[h][k] = e;
        sum += e;
    }
#pragma unroll
    for (int off = 16; off; off >>= 1) sum += __shfl_xor(sum, off);
    if (l32 == 0) sh_inv[h] = (sum > 0.f) ? 1.f / sum : 0.f;
    __syncthreads();
    // gather: per k one coalesced 1 KB row load; thread handles 2 bf16 of head h
    float a0 = 0.f, a1v = 0.f;
    const unsigned int* base = (const unsigned int*)Whb;
#pragma unroll 8
    for (int k = 0; k < c; ++k) {
        unsigned int u = base[(size_t)sh_m[k] * 256 + tid];
        float wgt = sh_s[h][k];
        a0  += wgt * us2f((unsigned short)(u & 0xFFFFu));
        a1v += wgt * us2f((unsigned short)(u >> 16));
    }
    const float inv = sh_inv[h];
    a0 *= inv; a1v *= inv;
    a0  = (a0  > 0.f) ? a0  : expm1f(a0);           // ELU
    a1v = (a1v > 0.f) ? a1v : expm1f(a1v);
    unsigned int o = (unsigned int)f2us(a0) | ((unsigned int)f2us(a1v) << 16);
    ((unsigned int*)catb)[(size_t)n * 256 + tid] = o;
}

// ---------------------------------------------------------------------------
// K3: Who = cat @ Wo via MFMA (hi+lo), fused g1/g2 (verified r9/r10).
// ---------------------------------------------------------------------------
__global__ __launch_bounds__(64) void who_mfma_g_kernel(
    const unsigned short* __restrict__ catb,
    const unsigned short* __restrict__ WtH, const unsigned short* __restrict__ WtL,
    const float* __restrict__ ao1c, const float* __restrict__ ao2c,
    float* __restrict__ Who, float* __restrict__ g1, float* __restrict__ g2)
{
    const int lane = threadIdx.x;
    const int quad = lane >> 4, l16 = lane & 15;
    const int row0 = blockIdx.x * 16;
    f32x4 acc = (f32x4){0.f, 0.f, 0.f, 0.f};
    for (int k0 = 0; k0 < DIN; k0 += 32) {
        bf16x8 a  = *(const bf16x8*)&catb[(size_t)(row0 + l16) * DIN + k0 + quad * 8];
        bf16x8 bh = *(const bf16x8*)&WtH[l16 * DIN + k0 + quad * 8];
        bf16x8 bl = *(const bf16x8*)&WtL[l16 * DIN + k0 + quad * 8];
        acc = __builtin_amdgcn_mfma_f32_16x16x32_bf16(a, bh, acc, 0, 0, 0);
        acc = __builtin_amdgcn_mfma_f32_16x16x32_bf16(a, bl, acc, 0, 0, 0);
    }
#pragma unroll
    for (int rr = 0; rr < 4; ++rr) {
        int row = row0 + quad * 4 + rr;
        float v = acc[rr];
        Who[row * DOUT + l16] = v;
        float p1 = v * ao1c[l16];
        float p2 = v * ao2c[l16];
#pragma unroll
        for (int off = 8; off; off >>= 1) {
            p1 += __shfl_xor(p1, off);
            p2 += __shfl_xor(p2, off);
        }
        if (l16 == 0) { g1[row] = p1; g2[row] = p2; }
    }
}

// ---------------------------------------------------------------------------
// K4: output sparse attention (verified r9/r10); fp32/bf16 store per dtype.
// ---------------------------------------------------------------------------
__global__ __launch_bounds__(64) void attn2_kernel(
    const void* __restrict__ adj,
    const float* __restrict__ Who,
    const float* __restrict__ g1, const float* __restrict__ g2,
    const int* __restrict__ cnt, const int* __restrict__ nbr,
    void* __restrict__ out)
{
    const int n = blockIdx.x;
    const int lane = threadIdx.x;
    const int quad = lane >> 4, l16 = lane & 15;
    __shared__ float sh_s[MAXN];
    __shared__ int sh_m[MAXN];
    const int c0 = cnt[n];
    const int c = (c0 < MAXN) ? c0 : MAXN;
    for (int k = lane; k < c; k += 64) sh_m[k] = nbr[(size_t)n * MAXN + k];
    __syncthreads();
    const float gn = g1[n];
    float mx = -1e30f;
    for (int k = lane; k < c; k += 64) {
        float s = gn + g2[sh_m[k]];
        s = (s >= 0.f) ? s : 0.2f * s;
        sh_s[k] = s;
        mx = fmaxf(mx, s);
    }
#pragma unroll
    for (int off = 32; off; off >>= 1) mx = fmaxf(mx, __shfl_xor(mx, off));
    __syncthreads();
    float sum = 0.f;
    for (int k = lane; k < c; k += 64) {
        float e = __expf(sh_s[k] - mx);
        sh_s[k] = e;
        sum += e;
    }
#pragma unroll
    for (int off = 32; off; off >>= 1) sum += __shfl_xor(sum, off);
    __syncthreads();
    const float inv = (sum > 0.f) ? 1.f / sum : 0.f;
    float accv = 0.f;
#pragma unroll 4
    for (int k = quad; k < c; k += 4)
        accv += sh_s[k] * Who[sh_m[k] * DOUT + l16];
    accv += __shfl_xor(accv, 16);
    accv += __shfl_xor(accv, 32);
    if (quad == 0) {
        float v = accv * inv;
        if (is_f32(adj)) ((float*)out)[n * DOUT + l16] = v;
        else             ((unsigned short*)out)[n * DOUT + l16] = f2us(v);
    }
}

__global__ void wsfail_kernel(float* __restrict__ out)
{
    if (threadIdx.x == 0) out[0] = 129.f;
}

// ---------------------------------------------------------------------------
extern "C" void kernel_launch(void* const* d_in, const int* in_sizes, int n_in,
                              void* d_out, int out_size, void* d_ws, size_t ws_size,
                              hipStream_t stream)
{
    const void* adj = d_in[0];
    const void* X   = d_in[1];
    const void* W   = d_in[2];
    const void* a1  = d_in[3];
    const void* a2  = d_in[4];
    const void* Wo  = d_in[5];
    const void* ao1 = d_in[6];
    const void* ao2 = d_in[7];

    const size_t NEEDED = 26400000;
    if (ws_size < NEEDED) { wsfail_kernel<<<1, 64, 0, stream>>>((float*)d_out); return; }

    int*   cnt  = (int*)d_ws;                        // 4096
    int*   nbr  = cnt + 4096;                        // 4096*512
    float* a1c  = (float*)(nbr + 2097152);           // 512
    float* a2c  = a1c + 512;                         // 512
    float* ao1c = a2c + 512;                         // 16
    float* ao2c = ao1c + 16;                         // 16
    float* f1   = ao2c + 16;                         // 32768
    float* f2   = f1 + 32768;                        // 32768
    float* Who  = f2 + 32768;                        // 65536
    float* g1   = Who + 65536;                       // 4096
    float* g2   = g1 + 4096;                         // 4096
    unsigned short* Whb  = (unsigned short*)(g2 + 4096);  // 2097152
    unsigned short* catb = Whb + 2097152;                 // 2097152
    unsigned short* Xhi  = catb + 2097152;                // 2097152
    unsigned short* Xlo  = Xhi + 2097152;                 // 2097152
    unsigned short* Wt   = Xlo + 2097152;                 // 262144
    unsigned short* WtH  = Wt + 262144;                   // 8192
    unsigned short* WtL  = WtH + 8192;                    // 8192

    prep_nbr_kernel<<<1024 + N_NODES, 256, 0, stream>>>(
        adj, X, W, a1, a2, Wo, ao1, ao2,
        Xhi, Xlo, Wt, WtH, WtL, a1c, a2c, ao1c, ao2c, cnt, nbr);
    wh_f12_kernel<<<dim3(NHEADS, N_NODES / 64), 256, 0, stream>>>(
        Xhi, Xlo, Wt, a1c, a2c, Whb, f1, f2);
    attn1_kernel<<<N_NODES, 256, 0, stream>>>(Whb, f1, f2, cnt, nbr, catb);
    who_mfma_g_kernel<<<N_NODES / 16, 64, 0, stream>>>(catb, WtH, WtL, ao1c, ao2c, Who, g1, g2);
    attn2_kernel<<<N_NODES, 64, 0, stream>>>(adj, Who, g1, g2, cnt, nbr, d_out);
}

// Round 12
// 162.583 us; speedup vs baseline: 1.6919x; 1.0172x over previous
//
#include <hip/hip_runtime.h>
#include <hip/hip_bf16.h>

#define N_NODES 4096
#define DIN     512
#define FDIM    64
#define NHEADS  8
#define DOUT    16
#define MAXN    512

typedef __attribute__((ext_vector_type(8))) short bf16x8;
typedef __attribute__((ext_vector_type(4))) float f32x4;

static __device__ __forceinline__ float us2f(unsigned short u) {
    union { unsigned int i; float f; } cv; cv.i = ((unsigned int)u) << 16; return cv.f;
}
static __device__ __forceinline__ unsigned short f2us(float v) {
    __hip_bfloat16 b = __float2bfloat16(v);
    return *(const unsigned short*)&b;
}
// dtype: adj[0][0] is a guaranteed self-loop 1.0; fp32 1.0f low ushort = 0 (verified r4-r11)
static __device__ __forceinline__ int is_f32(const void* adj) {
    return (((const unsigned short*)adj)[0] == 0) ? 1 : 0;
}

// ---------------------------------------------------------------------------
// K0: prep (blocks 0..1023) + row neighbor lists (blocks 1024..5119) merged.
// prep: X -> bf16, Wt[h][f][d] bf16, Wo^T hi/lo, small vecs fp32.
// ---------------------------------------------------------------------------
__global__ __launch_bounds__(256) void prep_nbr_kernel(
    const void* __restrict__ adj, const void* __restrict__ X, const void* __restrict__ W,
    const void* __restrict__ a1, const void* __restrict__ a2, const void* __restrict__ Wo,
    const void* __restrict__ ao1, const void* __restrict__ ao2,
    unsigned short* __restrict__ Xb, unsigned short* __restrict__ Wt,
    unsigned short* __restrict__ WtH, unsigned short* __restrict__ WtL,
    float* __restrict__ a1c, float* __restrict__ a2c,
    float* __restrict__ ao1c, float* __restrict__ ao2c,
    int* __restrict__ cnt, int* __restrict__ nbr)
{
    const int f32 = is_f32(adj);
    if (blockIdx.x >= 1024) {
        // ---- neighbor list for node n (verified r7-r11) ----
        const int n = blockIdx.x - 1024;
        __shared__ int c;
        if (threadIdx.x == 0) c = 0;
        __syncthreads();
        if (f32) {
            const uint4* row = (const uint4*)((const unsigned int*)adj + (size_t)n * N_NODES);
            for (int q = threadIdx.x; q < N_NODES / 4; q += 256) {
                uint4 v = row[q];
                int base = q * 4;
                if (v.x) { int p = atomicAdd(&c, 1); if (p < MAXN) nbr[(size_t)n * MAXN + p] = base + 0; }
                if (v.y) { int p = atomicAdd(&c, 1); if (p < MAXN) nbr[(size_t)n * MAXN + p] = base + 1; }
                if (v.z) { int p = atomicAdd(&c, 1); if (p < MAXN) nbr[(size_t)n * MAXN + p] = base + 2; }
                if (v.w) { int p = atomicAdd(&c, 1); if (p < MAXN) nbr[(size_t)n * MAXN + p] = base + 3; }
            }
        } else {
            const ushort4* row = (const ushort4*)((const unsigned short*)adj + (size_t)n * N_NODES);
            for (int q = threadIdx.x; q < N_NODES / 4; q += 256) {
                ushort4 v = row[q];
                int base = q * 4;
                if (v.x) { int p = atomicAdd(&c, 1); if (p < MAXN) nbr[(size_t)n * MAXN + p] = base + 0; }
                if (v.y) { int p = atomicAdd(&c, 1); if (p < MAXN) nbr[(size_t)n * MAXN + p] = base + 1; }
                if (v.z) { int p = atomicAdd(&c, 1); if (p < MAXN) nbr[(size_t)n * MAXN + p] = base + 2; }
                if (v.w) { int p = atomicAdd(&c, 1); if (p < MAXN) nbr[(size_t)n * MAXN + p] = base + 3; }
            }
        }
        __syncthreads();
        if (threadIdx.x == 0) cnt[n] = (c < MAXN) ? c : MAXN;
        return;
    }
    // ---- prep (blocks 0..1023) ----
    const int i0 = blockIdx.x * 256 + threadIdx.x;
    const int T = 1024 * 256;
    for (int i = i0; i < N_NODES * DIN; i += T) {
        float v = f32 ? ((const float*)X)[i] : us2f(((const unsigned short*)X)[i]);
        Xb[i] = f2us(v);
    }
    for (int i = i0; i < NHEADS * DIN * FDIM; i += T) {
        int hh = i >> 15, rem = i & 32767, d = rem >> 6, f = rem & 63;
        float v = f32 ? ((const float*)W)[i] : us2f(((const unsigned short*)W)[i]);
        Wt[((size_t)(hh * FDIM + f)) * DIN + d] = f2us(v);
    }
    for (int i = i0; i < DIN * DOUT; i += T) {
        int d = i >> 4, j = i & 15;
        float v = f32 ? ((const float*)Wo)[i] : us2f(((const unsigned short*)Wo)[i]);
        unsigned short hi = f2us(v);
        WtH[j * DIN + d] = hi;
        WtL[j * DIN + d] = f2us(v - us2f(hi));
    }
    if (i0 < 512) {
        a1c[i0] = f32 ? ((const float*)a1)[i0] : us2f(((const unsigned short*)a1)[i0]);
        a2c[i0] = f32 ? ((const float*)a2)[i0] : us2f(((const unsigned short*)a2)[i0]);
    }
    if (i0 < 16) {
        ao1c[i0] = f32 ? ((const float*)ao1)[i0] : us2f(((const unsigned short*)ao1)[i0]);
        ao2c[i0] = f32 ? ((const float*)ao2)[i0] : us2f(((const unsigned short*)ao2)[i0]);
    }
}

// ---------------------------------------------------------------------------
// K1: MFMA GEMM (fragments from global — verified r10/r11), single-MFMA K-loop
// (X plain bf16) + FUSED f1/f2 from fp32 accs. Whb layout [n][h][f].
// ---------------------------------------------------------------------------
__global__ __launch_bounds__(256) void wh_f12_kernel(
    const unsigned short* __restrict__ Xb, const unsigned short* __restrict__ Wt,
    const float* __restrict__ a1c, const float* __restrict__ a2c,
    unsigned short* __restrict__ Whb, float* __restrict__ f1, float* __restrict__ f2)
{
    const int h  = blockIdx.x;
    const int bm = blockIdx.y;
    const int w    = threadIdx.x >> 6;
    const int lane = threadIdx.x & 63;
    const int quad = lane >> 4;
    const int l16  = lane & 15;
    const int rowA = bm * 64 + w * 16 + l16;

    f32x4 acc[4];
#pragma unroll
    for (int j = 0; j < 4; ++j) acc[j] = (f32x4){0.f, 0.f, 0.f, 0.f};

    const unsigned short* xp = Xb + (size_t)rowA * DIN + quad * 8;
    const unsigned short* wb = Wt + (size_t)h * FDIM * DIN + quad * 8;
#pragma unroll 4
    for (int k0 = 0; k0 < DIN; k0 += 32) {
        bf16x8 a = *(const bf16x8*)(xp + k0);
#pragma unroll
        for (int j = 0; j < 4; ++j) {
            bf16x8 b = *(const bf16x8*)(wb + (size_t)(j * 16 + l16) * DIN + k0);
            acc[j] = __builtin_amdgcn_mfma_f32_16x16x32_bf16(a, b, acc[j], 0, 0, 0);
        }
    }
    // store Wh (bf16) and fused f1/f2 from fp32 accs
    float av1[4], av2[4];
#pragma unroll
    for (int j = 0; j < 4; ++j) {
        int col = j * 16 + l16;
        av1[j] = a1c[h * FDIM + col];
        av2[j] = a2c[h * FDIM + col];
#pragma unroll
        for (int rr = 0; rr < 4; ++rr) {
            int row = bm * 64 + w * 16 + quad * 4 + rr;
            Whb[((size_t)row * NHEADS + h) * FDIM + col] = f2us(acc[j][rr]);
        }
    }
#pragma unroll
    for (int rr = 0; rr < 4; ++rr) {
        float p1 = acc[0][rr] * av1[0] + acc[1][rr] * av1[1] + acc[2][rr] * av1[2] + acc[3][rr] * av1[3];
        float p2 = acc[0][rr] * av2[0] + acc[1][rr] * av2[1] + acc[2][rr] * av2[2] + acc[3][rr] * av2[3];
#pragma unroll
        for (int off = 8; off; off >>= 1) {   // reduce over the 16 l16 lanes
            p1 += __shfl_xor(p1, off);
            p2 += __shfl_xor(p2, off);
        }
        if (l16 == 0) {
            int row = bm * 64 + w * 16 + quad * 4 + rr;
            f1[h * N_NODES + row] = p1;
            f2[h * N_NODES + row] = p2;
        }
    }
}

// ---------------------------------------------------------------------------
// K2: layer-1 attention, all 8 heads per node (verified r10/r11).
// sh_s padded to 516 (bank-spread); coalesced 1 KB gather rows.
// ---------------------------------------------------------------------------
__global__ __launch_bounds__(256) void attn1_kernel(
    const unsigned short* __restrict__ Whb,
    const float* __restrict__ f1, const float* __restrict__ f2,
    const int* __restrict__ cnt, const int* __restrict__ nbr,
    unsigned short* __restrict__ catb)
{
    const int n = blockIdx.x;
    const int tid = threadIdx.x;
    __shared__ int sh_m[MAXN];
    __shared__ float sh_s[NHEADS][516];
    __shared__ float sh_inv[NHEADS];
    const int c0 = cnt[n];
    const int c = (c0 < MAXN) ? c0 : MAXN;
    for (int k = tid; k < c; k += 256) sh_m[k] = nbr[(size_t)n * MAXN + k];
    __syncthreads();
    const int h = tid >> 5;
    const int l32 = tid & 31;
    const float f1v = f1[h * N_NODES + n];
    float mx = -1e30f;
    for (int k = l32; k < c; k += 32) {
        float s = f1v + f2[h * N_NODES + sh_m[k]];
        s = (s >= 0.f) ? s : 0.2f * s;              // LeakyReLU(0.2)
        sh_s[h][k] = s;
        mx = fmaxf(mx, s);
    }
#pragma unroll
    for (int off = 16; off; off >>= 1) mx = fmaxf(mx, __shfl_xor(mx, off));
    __syncthreads();
    float sum = 0.f;
    for (int k = l32; k < c; k += 32) {
        float e = __expf(sh_s[h][k] - mx);
        sh_s[h][k] = e;
        sum += e;
    }
#pragma unroll
    for (int off = 16; off; off >>= 1) sum += __shfl_xor(sum, off);
    if (l32 == 0) sh_inv[h] = (sum > 0.f) ? 1.f / sum : 0.f;
    __syncthreads();
    // gather: per k one coalesced 1 KB row load; thread handles 2 bf16 of head h
    float a0 = 0.f, a1v = 0.f;
    const unsigned int* base = (const unsigned int*)Whb;
#pragma unroll 8
    for (int k = 0; k < c; ++k) {
        unsigned int u = base[(size_t)sh_m[k] * 256 + tid];
        float wgt = sh_s[h][k];
        a0  += wgt * us2f((unsigned short)(u & 0xFFFFu));
        a1v += wgt * us2f((unsigned short)(u >> 16));
    }
    const float inv = sh_inv[h];
    a0 *= inv; a1v *= inv;
    a0  = (a0  > 0.f) ? a0  : expm1f(a0);           // ELU
    a1v = (a1v > 0.f) ? a1v : expm1f(a1v);
    unsigned int o = (unsigned int)f2us(a0) | ((unsigned int)f2us(a1v) << 16);
    ((unsigned int*)catb)[(size_t)n * 256 + tid] = o;
}

// ---------------------------------------------------------------------------
// K3: Who = cat @ Wo via MFMA (hi+lo), fused g1/g2 (verified r9-r11).
// ---------------------------------------------------------------------------
__global__ __launch_bounds__(64) void who_mfma_g_kernel(
    const unsigned short* __restrict__ catb,
    const unsigned short* __restrict__ WtH, const unsigned short* __restrict__ WtL,
    const float* __restrict__ ao1c, const float* __restrict__ ao2c,
    float* __restrict__ Who, float* __restrict__ g1, float* __restrict__ g2)
{
    const int lane = threadIdx.x;
    const int quad = lane >> 4, l16 = lane & 15;
    const int row0 = blockIdx.x * 16;
    f32x4 acc = (f32x4){0.f, 0.f, 0.f, 0.f};
    for (int k0 = 0; k0 < DIN; k0 += 32) {
        bf16x8 a  = *(const bf16x8*)&catb[(size_t)(row0 + l16) * DIN + k0 + quad * 8];
        bf16x8 bh = *(const bf16x8*)&WtH[l16 * DIN + k0 + quad * 8];
        bf16x8 bl = *(const bf16x8*)&WtL[l16 * DIN + k0 + quad * 8];
        acc = __builtin_amdgcn_mfma_f32_16x16x32_bf16(a, bh, acc, 0, 0, 0);
        acc = __builtin_amdgcn_mfma_f32_16x16x32_bf16(a, bl, acc, 0, 0, 0);
    }
#pragma unroll
    for (int rr = 0; rr < 4; ++rr) {
        int row = row0 + quad * 4 + rr;
        float v = acc[rr];
        Who[row * DOUT + l16] = v;
        float p1 = v * ao1c[l16];
        float p2 = v * ao2c[l16];
#pragma unroll
        for (int off = 8; off; off >>= 1) {
            p1 += __shfl_xor(p1, off);
            p2 += __shfl_xor(p2, off);
        }
        if (l16 == 0) { g1[row] = p1; g2[row] = p2; }
    }
}

// ---------------------------------------------------------------------------
// K4: output sparse attention (verified r9-r11); fp32/bf16 store per dtype.
// ---------------------------------------------------------------------------
__global__ __launch_bounds__(64) void attn2_kernel(
    const void* __restrict__ adj,
    const float* __restrict__ Who,
    const float* __restrict__ g1, const float* __restrict__ g2,
    const int* __restrict__ cnt, const int* __restrict__ nbr,
    void* __restrict__ out)
{
    const int n = blockIdx.x;
    const int lane = threadIdx.x;
    const int quad = lane >> 4, l16 = lane & 15;
    __shared__ float sh_s[MAXN];
    __shared__ int sh_m[MAXN];
    const int c0 = cnt[n];
    const int c = (c0 < MAXN) ? c0 : MAXN;
    for (int k = lane; k < c; k += 64) sh_m[k] = nbr[(size_t)n * MAXN + k];
    __syncthreads();
    const float gn = g1[n];
    float mx = -1e30f;
    for (int k = lane; k < c; k += 64) {
        float s = gn + g2[sh_m[k]];
        s = (s >= 0.f) ? s : 0.2f * s;
        sh_s[k] = s;
        mx = fmaxf(mx, s);
    }
#pragma unroll
    for (int off = 32; off; off >>= 1) mx = fmaxf(mx, __shfl_xor(mx, off));
    __syncthreads();
    float sum = 0.f;
    for (int k = lane; k < c; k += 64) {
        float e = __expf(sh_s[k] - mx);
        sh_s[k] = e;
        sum += e;
    }
#pragma unroll
    for (int off = 32; off; off >>= 1) sum += __shfl_xor(sum, off);
    __syncthreads();
    const float inv = (sum > 0.f) ? 1.f / sum : 0.f;
    float accv = 0.f;
#pragma unroll 4
    for (int k = quad; k < c; k += 4)
        accv += sh_s[k] * Who[sh_m[k] * DOUT + l16];
    accv += __shfl_xor(accv, 16);
    accv += __shfl_xor(accv, 32);
    if (quad == 0) {
        float v = accv * inv;
        if (is_f32(adj)) ((float*)out)[n * DOUT + l16] = v;
        else             ((unsigned short*)out)[n * DOUT + l16] = f2us(v);
    }
}

__global__ void wsfail_kernel(float* __restrict__ out)
{
    if (threadIdx.x == 0) out[0] = 129.f;
}

// ---------------------------------------------------------------------------
extern "C" void kernel_launch(void* const* d_in, const int* in_sizes, int n_in,
                              void* d_out, int out_size, void* d_ws, size_t ws_size,
                              hipStream_t stream)
{
    const void* adj = d_in[0];
    const void* X   = d_in[1];
    const void* W   = d_in[2];
    const void* a1  = d_in[3];
    const void* a2  = d_in[4];
    const void* Wo  = d_in[5];
    const void* ao1 = d_in[6];
    const void* ao2 = d_in[7];

    const size_t NEEDED = 22000000;
    if (ws_size < NEEDED) { wsfail_kernel<<<1, 64, 0, stream>>>((float*)d_out); return; }

    int*   cnt  = (int*)d_ws;                        // 4096
    int*   nbr  = cnt + 4096;                        // 4096*512
    float* a1c  = (float*)(nbr + 2097152);           // 512
    float* a2c  = a1c + 512;                         // 512
    float* ao1c = a2c + 512;                         // 16
    float* ao2c = ao1c + 16;                         // 16
    float* f1   = ao2c + 16;                         // 32768
    float* f2   = f1 + 32768;                        // 32768
    float* Who  = f2 + 32768;                        // 65536
    float* g1   = Who + 65536;                       // 4096
    float* g2   = g1 + 4096;                         // 4096
    unsigned short* Whb  = (unsigned short*)(g2 + 4096);  // 2097152
    unsigned short* catb = Whb + 2097152;                 // 2097152
    unsigned short* Xb   = catb + 2097152;                // 2097152
    unsigned short* Wt   = Xb + 2097152;                  // 262144
    unsigned short* WtH  = Wt + 262144;                   // 8192
    unsigned short* WtL  = WtH + 8192;                    // 8192

    prep_nbr_kernel<<<1024 + N_NODES, 256, 0, stream>>>(
        adj, X, W, a1, a2, Wo, ao1, ao2,
        Xb, Wt, WtH, WtL, a1c, a2c, ao1c, ao2c, cnt, nbr);
    wh_f12_kernel<<<dim3(NHEADS, N_NODES / 64), 256, 0, stream>>>(
        Xb, Wt, a1c, a2c, Whb, f1, f2);
    attn1_kernel<<<N_NODES, 256, 0, stream>>>(Whb, f1, f2, cnt, nbr, catb);
    who_mfma_g_kernel<<<N_NODES / 16, 64, 0, stream>>>(catb, WtH, WtL, ao1c, ao2c, Who, g1, g2);
    attn2_kernel<<<N_NODES, 64, 0, stream>>>(adj, Who, g1, g2, cnt, nbr, d_out);
}